// Round 11
// baseline (215.259 us; speedup 1.0000x reference)
//
#include <hip/hip_runtime.h>
#include <hip/hip_bf16.h>
#include <math.h>

#define D_MODEL 1024
#define D_INNER 2048
#define D_STATE 128
#define NHEADS 32
#define HEADDIM 64
#define CHUNK 64
#define B_SZ 2
#define LSEQ 2048
#define BL (B_SZ*LSEQ)                              // 4096
#define DPROJ (2*D_INNER + 2*D_STATE + NHEADS)      // 4384
#define CONV_DIM (D_INNER + 2*D_STATE)              // 2304
#define NCHUNK (LSEQ/CHUNK)                         // 32
#define NPAD 4608                                   // DPROJ padded to x256
#define EPSF 1e-5f

typedef __attribute__((ext_vector_type(8))) _Float16 half8;
typedef __attribute__((ext_vector_type(4))) _Float16 half4;
typedef __attribute__((ext_vector_type(4))) float f32x4;

__device__ __forceinline__ float siluf(float v){ return v / (1.0f + expf(-v)); }
__device__ __forceinline__ float softplusf(float v){ return v > 20.0f ? v : log1pf(expf(v)); }
__device__ __forceinline__ unsigned short f2h(float x){
  union { _Float16 h; unsigned short u; } v; v.h = (_Float16)x;
  return v.u;
}
__device__ __forceinline__ float h2f(unsigned short x){
  union { unsigned short u; _Float16 h; } v; v.u = x;
  return (float)v.h;
}
__device__ __forceinline__ _Float16 h2h(unsigned short x){
  union { unsigned short u; _Float16 h; } v; v.u = x;
  return v.h;
}

typedef const __attribute__((address_space(1))) void gvoid_t;
typedef __attribute__((address_space(3))) void lvoid_t;
__device__ __forceinline__ void gl_lds16(const void* gsrc, void* ldst) {
  gvoid_t* g = reinterpret_cast<gvoid_t*>((uintptr_t)gsrc);
  lvoid_t* l = reinterpret_cast<lvoid_t*>((unsigned int)(uintptr_t)ldst);
  __builtin_amdgcn_global_load_lds(g, l, 16, 0, 0);
}

// ---------- fp32 -> fp16 converters ----------
__global__ void cvt_f16(const float* __restrict__ in, unsigned short* __restrict__ out, int n4) {
  int i = blockIdx.x*256 + threadIdx.x;
  if (i >= n4) return;
  float4 v = *(const float4*)(in + (size_t)i*4);
  ushort4 o; o.x=f2h(v.x); o.y=f2h(v.y); o.z=f2h(v.z); o.w=f2h(v.w);
  *(ushort4*)(out + (size_t)i*4) = o;
}

__global__ void cvt_pad(const float* __restrict__ in, unsigned short* __restrict__ out,
                        int rows_in, int total4, int kdim4) {
  int i = blockIdx.x*256 + threadIdx.x;
  if (i >= total4) return;
  int row = i / kdim4;
  ushort4 o; o.x=0; o.y=0; o.z=0; o.w=0;
  if (row < rows_in) {
    float4 v = *(const float4*)(in + (size_t)i*4);
    o.x=f2h(v.x); o.y=f2h(v.y); o.z=f2h(v.z); o.w=f2h(v.w);
  }
  *(ushort4*)(out + (size_t)i*4) = o;
}

// ---------- 256x256 fp16 MFMA GEMM: 8 waves, BK=64, dbuf LDS, counted vmcnt ----------
// C[m,n] = sum_k A[m,k]*W[n,k]. A: M x K (M%256==0), W: Npad x K (grid.x=Npad/256).
// LDS layout per buf: A[256][64], B[256][64] fp16, k-chunk XOR-swizzled: kc' = kc ^ (row&7).
template<int OUT_F16>
__global__ __launch_bounds__(512, 2) void gemm_f16_256(const unsigned short* __restrict__ A,
    const unsigned short* __restrict__ W, void* __restrict__ Cv, int N, int K) {
  __shared__ unsigned short lds[2*32768];           // 128 KB
  const int t   = threadIdx.x;
  const int wid = t >> 6, l = t & 63;
  const int nwg = gridDim.x * gridDim.y;
  int bid = blockIdx.y * gridDim.x + blockIdx.x;
  int swz = (bid & 7) * (nwg >> 3) + (bid >> 3);    // XCD-chunked (nwg%8==0)
  const int m0 = (swz / gridDim.x) * 256;
  const int n0 = (swz % gridDim.x) * 256;
  const int wm = wid >> 2, wn = wid & 3;            // 2 x 4 wave grid
  const int fr = l & 15, cg = l >> 4;
  const int NT = K >> 6;

  // staging map: 4 chunks per matrix per thread; chunk c -> row c/8, slot c%8,
  // source k-block = slot ^ (row&7)  (inverse of the read-side swizzle)
  int srow[4], scol[4];
  #pragma unroll
  for (int i=0;i<4;++i){
    int c = i*512 + t;
    int r = c >> 3, s = c & 7;
    srow[i] = r; scol[i] = (s ^ (r & 7)) * 8;
  }

#define STG256(tile, buf) { \
    int kk = (tile) << 6; \
    char* La_ = (char*)lds + (buf)*65536; \
    char* Lb_ = La_ + 32768; \
    gl_lds16(A + (size_t)(m0+srow[0])*K + kk + scol[0], La_ + (0*512+t)*16); \
    gl_lds16(A + (size_t)(m0+srow[1])*K + kk + scol[1], La_ + (1*512+t)*16); \
    gl_lds16(A + (size_t)(m0+srow[2])*K + kk + scol[2], La_ + (2*512+t)*16); \
    gl_lds16(A + (size_t)(m0+srow[3])*K + kk + scol[3], La_ + (3*512+t)*16); \
    gl_lds16(W + (size_t)(n0+srow[0])*K + kk + scol[0], Lb_ + (0*512+t)*16); \
    gl_lds16(W + (size_t)(n0+srow[1])*K + kk + scol[1], Lb_ + (1*512+t)*16); \
    gl_lds16(W + (size_t)(n0+srow[2])*K + kk + scol[2], Lb_ + (2*512+t)*16); \
    gl_lds16(W + (size_t)(n0+srow[3])*K + kk + scol[3], Lb_ + (3*512+t)*16); \
  }

  f32x4 acc[8][4] = {};
  STG256(0, 0);
  for (int tt = 0; tt < NT; ++tt) {
    int buf = tt & 1;
    if (tt + 1 < NT) {
      STG256(tt+1, buf^1);                          // prev barrier guarantees buf^1 free
      asm volatile("s_waitcnt vmcnt(8)" ::: "memory");   // tile tt landed; t+1 in flight
    } else {
      asm volatile("s_waitcnt vmcnt(0)" ::: "memory");
    }
    __builtin_amdgcn_s_barrier();                   // all waves see tile tt data
    asm volatile("" ::: "memory");
    const char* La = (const char*)lds + buf*65536;
    const char* Lb = La + 32768;
    #pragma unroll
    for (int ks = 0; ks < 2; ++ks) {
      half8 bfv[4];
      #pragma unroll
      for (int n=0;n<4;++n){
        int r = wn*64 + n*16 + fr;
        int kc = (ks*4 + cg) ^ (r & 7);
        bfv[n] = *(const half8*)(Lb + r*128 + kc*16);
      }
      __builtin_amdgcn_s_setprio(1);
      #pragma unroll
      for (int m=0;m<8;++m){
        int r = wm*128 + m*16 + fr;
        int kc = (ks*4 + cg) ^ (r & 7);
        half8 af = *(const half8*)(La + r*128 + kc*16);
        #pragma unroll
        for (int n=0;n<4;++n)
          acc[m][n] = __builtin_amdgcn_mfma_f32_16x16x32_f16(af, bfv[n], acc[m][n], 0, 0, 0);
      }
      __builtin_amdgcn_s_setprio(0);
    }
    asm volatile("s_waitcnt lgkmcnt(0)" ::: "memory");
    __builtin_amdgcn_s_barrier();                   // reads done; next iter may overwrite buf^1
    asm volatile("" ::: "memory");
  }
#undef STG256

  const int crow0 = m0 + wm*128 + cg*4;
  const int ccol0 = n0 + wn*64 + fr;
  #pragma unroll
  for (int m=0;m<8;++m){
    #pragma unroll
    for (int n=0;n<4;++n){
      int col = ccol0 + n*16;
      if (col < N) {
        if (OUT_F16) {
          unsigned short* cp = (unsigned short*)Cv + (size_t)(crow0 + m*16)*N + col;
          #pragma unroll
          for (int j=0;j<4;++j) cp[(size_t)j*N] = f2h(acc[m][n][j]);
        } else {
          float* cp = (float*)Cv + (size_t)(crow0 + m*16)*N + col;
          #pragma unroll
          for (int j=0;j<4;++j) cp[(size_t)j*N] = acc[m][n][j];
        }
      }
    }
  }
}

// ---------- 128x128 pipelined GEMM (kept for GEMM2: grid 8x32 covers the chip) ----------
template<int OUT_F16>
__global__ __launch_bounds__(256) void gemm_f16_pipe(const unsigned short* __restrict__ A,
    const unsigned short* __restrict__ W, void* __restrict__ Cv, int N, int K) {
  __shared__ unsigned short lds[5*2*4096];          // 80 KB
  const int t   = threadIdx.x;
  const int wid = t >> 6, l = t & 63;
  const int nwg = gridDim.x * gridDim.y;
  int bid = blockIdx.y * gridDim.x + blockIdx.x;
  int swz = (bid & 7) * (nwg >> 3) + (bid >> 3);
  const int m0 = (swz / gridDim.x) * 128;
  const int n0 = (swz % gridDim.x) * 128;
  const int wr = wid >> 1, wc = wid & 1;
  const int fr = l & 15, cg = l >> 4;
  const int NT = K >> 5;

  int srow[2]; int scol[2];
  #pragma unroll
  for (int i=0;i<2;++i){
    int s = i*256 + t;
    int r = s >> 2, c = s & 3;
    int sw = (r + (r>>2)) & 3;
    srow[i] = r; scol[i] = (c ^ sw) * 8;
  }
  const unsigned short* Abase = A + (size_t)m0 * K;
  const unsigned short* Wbase = W + (size_t)n0 * K;

#define STAGE(tt, slot) { \
    int kk = (tt) << 5; \
    unsigned short* La = &lds[(slot)*8192]; \
    unsigned short* Lb = &lds[(slot)*8192 + 4096]; \
    gl_lds16(Abase + (size_t)srow[0]*K + kk + scol[0], (char*)La + (0*256+t)*16); \
    gl_lds16(Abase + (size_t)srow[1]*K + kk + scol[1], (char*)La + (1*256+t)*16); \
    gl_lds16(Wbase + (size_t)srow[0]*K + kk + scol[0], (char*)Lb + (0*256+t)*16); \
    gl_lds16(Wbase + (size_t)srow[1]*K + kk + scol[1], (char*)Lb + (1*256+t)*16); \
  }

  f32x4 acc[4][4] = {};
  STAGE(0, 0);
  STAGE(1, 1);
  STAGE(2, 2);
  STAGE(3, 3);
  asm volatile("s_waitcnt vmcnt(12)" ::: "memory");
  __builtin_amdgcn_s_barrier();
  asm volatile("" ::: "memory");

  int cs = 0;
  for (int tt = 0; tt < NT; ++tt) {
    int ss = (cs == 0) ? 4 : cs - 1;
    if (tt + 4 < NT) STAGE(tt+4, ss);
    const unsigned short* La = &lds[cs*8192];
    const unsigned short* Lb = &lds[cs*8192 + 4096];
    half8 af[4], bfv[4];
    #pragma unroll
    for (int m=0;m<4;++m){
      int r = wr*64 + m*16 + fr;
      int sw = (r + (r>>2)) & 3;
      af[m] = *(const half8*)&La[(r*4 + (cg ^ sw))*8];
    }
    #pragma unroll
    for (int n=0;n<4;++n){
      int r = wc*64 + n*16 + fr;
      int sw = (r + (r>>2)) & 3;
      bfv[n] = *(const half8*)&Lb[(r*4 + (cg ^ sw))*8];
    }
    __builtin_amdgcn_s_setprio(1);
    #pragma unroll
    for (int m=0;m<4;++m)
      #pragma unroll
      for (int n=0;n<4;++n)
        acc[m][n] = __builtin_amdgcn_mfma_f32_16x16x32_f16(af[m], bfv[n], acc[m][n], 0, 0, 0);
    __builtin_amdgcn_s_setprio(0);
    if (tt + 1 < NT) {
      if      (tt + 4 < NT) { asm volatile("s_waitcnt vmcnt(12)" ::: "memory"); }
      else if (tt + 3 < NT) { asm volatile("s_waitcnt vmcnt(8)"  ::: "memory"); }
      else if (tt + 2 < NT) { asm volatile("s_waitcnt vmcnt(4)"  ::: "memory"); }
      else                  { asm volatile("s_waitcnt vmcnt(0)"  ::: "memory"); }
      __builtin_amdgcn_s_barrier();
      asm volatile("" ::: "memory");
    }
    cs = (cs == 4) ? 0 : cs + 1;
  }
#undef STAGE

  const int crow = m0 + wr*64 + (l >> 4) * 4;
  const int ccol0 = n0 + wc*64 + fr;
  #pragma unroll
  for (int m = 0; m < 4; ++m) {
    #pragma unroll
    for (int n = 0; n < 4; ++n) {
      int col = ccol0 + n*16;
      if (col < N) {
        if (OUT_F16) {
          unsigned short* cp = (unsigned short*)Cv + (size_t)(crow + m*16)*N + col;
          #pragma unroll
          for (int j = 0; j < 4; ++j) cp[(size_t)j*N] = f2h(acc[m][n][j]);
        } else {
          float* cp = (float*)Cv + (size_t)(crow + m*16)*N + col;
          #pragma unroll
          for (int j = 0; j < 4; ++j) cp[(size_t)j*N] = acc[m][n][j];
        }
      }
    }
  }
}

// ---------- dt from GEMM1 output: softplus(zx[...,4352+h] + bias) ----------
__global__ void dtx_kernel(const unsigned short* __restrict__ zx,
    const float* __restrict__ dt_bias, float* __restrict__ dt) {
  int i = blockIdx.x*256 + threadIdx.x;             // over BL*NHEADS
  if (i >= BL*NHEADS) return;
  int row = i >> 5, h = i & 31;
  float v = h2f(zx[(size_t)row*DPROJ + (2*D_INNER + 2*D_STATE) + h]) + dt_bias[h];
  dt[i] = softplusf(v);
}

// A_cum[(b*32+h)*32+c][l]
__global__ __launch_bounds__(64) void acum_kernel(const float* __restrict__ dt,
    const float* __restrict__ A_log, float* __restrict__ A_cum) {
  int blk = blockIdx.x;                             // (b*32+h)*32+c
  int c = blk & 31, h = (blk >> 5) & 31, b = blk >> 10;
  int l = threadIdx.x;
  __shared__ float sv[64];
  int row = b*LSEQ + c*CHUNK + l;
  float a = -expf(A_log[h]);
  sv[l] = a * dt[row*NHEADS + h];
  __syncthreads();
  if (l == 0) {
    float s = 0.f;
    for (int i=0;i<64;++i){ s += sv[i]; sv[i] = s; }
  }
  __syncthreads();
  A_cum[blk*64 + l] = sv[l];
}

// causal depthwise conv (K=4) + bias + silu; fp16 in/out; 8 rows x 4 channels per thread
__global__ __launch_bounds__(256) void conv8_kernel(const unsigned short* __restrict__ zx,
    const float* __restrict__ w, const float* __restrict__ bias, unsigned short* __restrict__ xBC) {
  int idx = blockIdx.x*256 + threadIdx.x;           // over (BL/8) * (CONV_DIM/4)
  if (idx >= (BL/8)*(CONV_DIM/4)) return;
  int c4  = idx % (CONV_DIM/4);
  int rb  = idx / (CONV_DIM/4);
  int ch  = c4 * 4;
  int row0 = rb * 8;
  int l0   = row0 & (LSEQ-1);
  float4 r[11];
  #pragma unroll
  for (int jj=0;jj<11;++jj){
    int li = l0 + jj - 3;
    if (li >= 0) {
      ushort4 v = *(const ushort4*)&zx[(size_t)(row0 + jj - 3)*DPROJ + D_INNER + ch];
      r[jj] = make_float4(h2f(v.x), h2f(v.y), h2f(v.z), h2f(v.w));
    } else r[jj] = make_float4(0.f,0.f,0.f,0.f);
  }
  float4 wv[4];
  #pragma unroll
  for (int c=0;c<4;++c) wv[c] = *(const float4*)&w[(ch+c)*4];
  float4 bv = *(const float4*)&bias[ch];
  #pragma unroll
  for (int j=0;j<8;++j){
    float4 acc = bv;
    acc.x += wv[0].x*r[j].x + wv[0].y*r[j+1].x + wv[0].z*r[j+2].x + wv[0].w*r[j+3].x;
    acc.y += wv[1].x*r[j].y + wv[1].y*r[j+1].y + wv[1].z*r[j+2].y + wv[1].w*r[j+3].y;
    acc.z += wv[2].x*r[j].z + wv[2].y*r[j+1].z + wv[2].z*r[j+2].z + wv[2].w*r[j+3].z;
    acc.w += wv[3].x*r[j].w + wv[3].y*r[j+1].w + wv[3].z*r[j+2].w + wv[3].w*r[j+3].w;
    ushort4 o; o.x=f2h(siluf(acc.x)); o.y=f2h(siluf(acc.y)); o.z=f2h(siluf(acc.z)); o.w=f2h(siluf(acc.w));
    *(ushort4*)&xBC[(size_t)(row0+j)*CONV_DIM + ch] = o;
  }
}

// G[b,c][l][s] = sum_n C[l,n] * B[s,n]; 4 blocks per (b,c)
__global__ __launch_bounds__(256) void g_kernel(const unsigned short* __restrict__ xBC, float* __restrict__ G) {
  int blk = blockIdx.x >> 2;                        // b*32 + c
  int lq  = blockIdx.x & 3;
  int b = blk >> 5, c = blk & 31;
  __shared__ float Bsh[64][129];
  int t = threadIdx.x;
  int row0 = b*LSEQ + c*CHUNK;
  for (int j=0;j<32;++j){
    int lin = j*256 + t;
    int s = lin >> 7, n = lin & 127;
    Bsh[s][n] = h2f(xBC[(size_t)(row0+s)*CONV_DIM + D_INNER + n]);
  }
  __syncthreads();
  int l = lq*16 + (t >> 4), s0 = (t & 15) * 4;
  const unsigned short* Cp = &xBC[(size_t)(row0+l)*CONV_DIM + D_INNER + D_STATE];
  float acc[4] = {};
  for (int n=0;n<128;++n){
    float cv = h2f(Cp[n]);
    #pragma unroll
    for (int j=0;j<4;++j) acc[j] += cv * Bsh[s0+j][n];
  }
  float* Gp = &G[(size_t)blk*4096 + l*64 + s0];
  #pragma unroll
  for (int j=0;j<4;++j) Gp[j] = acc[j];
}

// ---------- MFMA states (fp16 out) ----------
__global__ __launch_bounds__(256) void states_mfma(const unsigned short* __restrict__ xBC,
    const float* __restrict__ dt, const float* __restrict__ A_cum, unsigned short* __restrict__ states) {
  int blk = blockIdx.x;                             // (b*32+c)*32+h
  int h = blk & 31, c = (blk>>5)&31, b = blk>>10;
  __shared__ _Float16 Bt[128][72];                  // [n][s]
  __shared__ _Float16 xdT[64][72];                  // [p][s]
  __shared__ float Ac[64], dtl[64];
  int t = threadIdx.x;
  int wid = t >> 6, ln = t & 63;
  int row0 = b*LSEQ + c*CHUNK;
  if (t < 64){ Ac[t] = A_cum[((b*32+h)*32 + c)*64 + t]; dtl[t] = dt[(row0+t)*NHEADS + h]; }
  __syncthreads();
  float AcL = Ac[63];
  #pragma unroll
  for (int j=0;j<32;++j){
    int lin = j*256+t; int s = lin>>7, n = lin&127;
    Bt[n][s] = h2h(xBC[(size_t)(row0+s)*CONV_DIM + D_INNER + n]);
  }
  #pragma unroll
  for (int j=0;j<16;++j){
    int lin = j*256+t; int s = lin>>6, p = lin&63;
    xdT[p][s] = (_Float16)(h2f(xBC[(size_t)(row0+s)*CONV_DIM + h*HEADDIM + p]) * dtl[s] * expf(AcL - Ac[s]));
  }
  __syncthreads();
  const int fr = ln & 15, fk = (ln >> 4) * 8;
  f32x4 acc[4][2] = {};
  #pragma unroll
  for (int ks = 0; ks < 2; ++ks){
    half8 a[4], bb[2];
    #pragma unroll
    for (int pt=0;pt<4;++pt) a[pt] = *(const half8*)&xdT[pt*16+fr][ks*32+fk];
    #pragma unroll
    for (int nt=0;nt<2;++nt) bb[nt] = *(const half8*)&Bt[(wid*2+nt)*16+fr][ks*32+fk];
    #pragma unroll
    for (int pt=0;pt<4;++pt)
      #pragma unroll
      for (int nt=0;nt<2;++nt)
        acc[pt][nt] = __builtin_amdgcn_mfma_f32_16x16x32_f16(a[pt], bb[nt], acc[pt][nt], 0, 0, 0);
  }
  unsigned short* Sp = &states[(size_t)blk*8192];
  #pragma unroll
  for (int pt=0;pt<4;++pt){
    int p0 = pt*16 + (ln>>4)*4;
    #pragma unroll
    for (int nt=0;nt<2;++nt){
      int n = (wid*2+nt)*16 + fr;
      #pragma unroll
      for (int j=0;j<4;++j) Sp[(p0+j)*128 + n] = f2h(acc[pt][nt][j]);
    }
  }
}

// inter-chunk scan (fp16 storage, fp32 accumulator), split 8-way
__global__ __launch_bounds__(256) void scan_kernel(const float* __restrict__ A_cum,
                                                   unsigned short* __restrict__ states) {
  int g  = blockIdx.x & 7;
  int bh = blockIdx.x >> 3;
  int b = bh >> 5, h = bh & 31;
  int t = threadIdx.x;
  float S[4];
  #pragma unroll
  for (int j=0;j<4;++j) S[j] = 0.f;
  for (int c=0;c<NCHUNK;++c){
    float decay = expf(A_cum[((b*32+h)*32 + c)*64 + 63]);
    unsigned short* Sp = &states[(size_t)((b*32+c)*32 + h)*8192];
    #pragma unroll
    for (int j=0;j<4;++j){
      float tmp = h2f(Sp[(g*4+j)*256+t]);
      Sp[(g*4+j)*256+t] = f2h(S[j]);
      S[j] = S[j]*decay + tmp;
    }
  }
}

// ---------- MFMA Y ----------
__global__ __launch_bounds__(256) void y_mfma(const unsigned short* __restrict__ xBC,
    const unsigned short* __restrict__ zx, const float* __restrict__ dt,
    const float* __restrict__ A_cum, const float* __restrict__ G,
    const unsigned short* __restrict__ states, const float* __restrict__ Dp,
    unsigned short* __restrict__ y_pre) {
  int blk = blockIdx.x;                             // (b*32+c)*32+h
  int h = blk & 31, c = (blk>>5)&31, b = blk>>10;
  __shared__ _Float16 Cl[64][136];
  __shared__ _Float16 Sin[64][136];
  __shared__ _Float16 Ms[64][72];
  __shared__ _Float16 xdT[64][72];
  __shared__ float Ac[64], dtl[64];
  int t = threadIdx.x;
  int wid = t >> 6, ln = t & 63;
  int row0 = b*LSEQ + c*CHUNK;
  if (t < 64){ Ac[t] = A_cum[((b*32+h)*32 + c)*64 + t]; dtl[t] = dt[(row0+t)*NHEADS + h]; }
  __syncthreads();
  #pragma unroll
  for (int j=0;j<32;++j){
    int lin = j*256+t; int l = lin>>7, n = lin&127;
    Cl[l][n] = (_Float16)(h2f(xBC[(size_t)(row0+l)*CONV_DIM + D_INNER + D_STATE + n]) * expf(Ac[l]));
  }
  {
    const unsigned short* Sg = &states[(size_t)blk*8192];
    #pragma unroll
    for (int j=0;j<8;++j){
      int elem = (j*256+t)*4; int p = elem>>7, n = elem&127;
      ushort4 v = *(const ushort4*)&Sg[elem];
      half4 hv = { h2h(v.x), h2h(v.y), h2h(v.z), h2h(v.w) };
      *(half4*)&Sin[p][n] = hv;
    }
  }
  #pragma unroll
  for (int j=0;j<16;++j){
    int lin = j*256+t; int s = lin>>6, p = lin&63;
    xdT[p][s] = (_Float16)(h2f(xBC[(size_t)(row0+s)*CONV_DIM + h*HEADDIM + p]) * dtl[s]);
  }
  {
    const float* Gp = &G[(size_t)(b*32+c)*4096];
    #pragma unroll
    for (int j=0;j<16;++j){
      int lin = j*256+t; int l = lin>>6, s = lin&63;
      Ms[l][s] = (s <= l) ? (_Float16)(Gp[l*64+s] * expf(Ac[l]-Ac[s])) : (_Float16)0.f;
    }
  }
  __syncthreads();
  const int wr = wid >> 1, wc = wid & 1;
  const int fr = ln & 15, fk = (ln >> 4) * 8;
  f32x4 acc[2][2] = {};
  #pragma unroll
  for (int ks = 0; ks < 4; ++ks){
    half8 a[2], bb[2];
    #pragma unroll
    for (int lt=0;lt<2;++lt) a[lt] = *(const half8*)&Cl[(wr*2+lt)*16+fr][ks*32+fk];
    #pragma unroll
    for (int pt=0;pt<2;++pt) bb[pt] = *(const half8*)&Sin[(wc*2+pt)*16+fr][ks*32+fk];
    #pragma unroll
    for (int lt=0;lt<2;++lt)
      #pragma unroll
      for (int pt=0;pt<2;++pt)
        acc[lt][pt] = __builtin_amdgcn_mfma_f32_16x16x32_f16(a[lt], bb[pt], acc[lt][pt], 0, 0, 0);
  }
  #pragma unroll
  for (int ks = 0; ks < 2; ++ks){
    half8 a[2], bb[2];
    #pragma unroll
    for (int lt=0;lt<2;++lt) a[lt] = *(const half8*)&Ms[(wr*2+lt)*16+fr][ks*32+fk];
    #pragma unroll
    for (int pt=0;pt<2;++pt) bb[pt] = *(const half8*)&xdT[(wc*2+pt)*16+fr][ks*32+fk];
    #pragma unroll
    for (int lt=0;lt<2;++lt)
      #pragma unroll
      for (int pt=0;pt<2;++pt)
        acc[lt][pt] = __builtin_amdgcn_mfma_f32_16x16x32_f16(a[lt], bb[pt], acc[lt][pt], 0, 0, 0);
  }
  float Dh = Dp[h];
  #pragma unroll
  for (int lt=0;lt<2;++lt){
    int l0 = (wr*2+lt)*16 + (ln>>4)*4;
    #pragma unroll
    for (int pt=0;pt<2;++pt){
      int p = (wc*2+pt)*16 + fr;
      #pragma unroll
      for (int j=0;j<4;++j){
        int grow = row0 + l0 + j;
        float x = h2f(xBC[(size_t)grow*CONV_DIM + h*HEADDIM + p]);
        float z = h2f(zx[(size_t)grow*DPROJ + h*HEADDIM + p]);
        y_pre[(size_t)grow*D_INNER + h*HEADDIM + p] = f2h((acc[lt][pt][j] + x*Dh) * siluf(z));
      }
    }
  }
}

// RMS norm * norm_w, fp16 in -> fp16 out, contiguous 8/thread
__global__ __launch_bounds__(256) void rms_kernel(const unsigned short* __restrict__ y,
    const float* __restrict__ norm_w, unsigned short* __restrict__ yh) {
  int row = blockIdx.x;
  int t = threadIdx.x;
  const unsigned short* yr = y + (size_t)row*D_INNER + t*8;
  ushort4 a = *(const ushort4*)yr;
  ushort4 bq = *(const ushort4*)(yr+4);
  float v[8];
  v[0]=h2f(a.x); v[1]=h2f(a.y); v[2]=h2f(a.z); v[3]=h2f(a.w);
  v[4]=h2f(bq.x); v[5]=h2f(bq.y); v[6]=h2f(bq.z); v[7]=h2f(bq.w);
  float ss = 0.f;
  #pragma unroll
  for (int j=0;j<8;++j) ss += v[j]*v[j];
  #pragma unroll
  for (int off=32; off>0; off>>=1) ss += __shfl_down(ss, off, 64);
  __shared__ float wsum[4];
  int wid = t >> 6, lane = t & 63;
  if (lane == 0) wsum[wid] = ss;
  __syncthreads();
  if (t == 0) wsum[0] = rsqrtf((wsum[0]+wsum[1]+wsum[2]+wsum[3])/D_INNER + EPSF);
  __syncthreads();
  float sc = wsum[0];
  float4 w0 = *(const float4*)&norm_w[t*8];
  float4 w1 = *(const float4*)&norm_w[t*8+4];
  ushort4 o0, o1;
  o0.x=f2h(v[0]*sc*w0.x); o0.y=f2h(v[1]*sc*w0.y); o0.z=f2h(v[2]*sc*w0.z); o0.w=f2h(v[3]*sc*w0.w);
  o1.x=f2h(v[4]*sc*w1.x); o1.y=f2h(v[5]*sc*w1.y); o1.z=f2h(v[6]*sc*w1.z); o1.w=f2h(v[7]*sc*w1.w);
  unsigned short* yo = yh + (size_t)row*D_INNER + t*8;
  *(ushort4*)yo = o0;
  *(ushort4*)(yo+4) = o1;
}

extern "C" void kernel_launch(void* const* d_in, const int* in_sizes, int n_in,
                              void* d_out, int out_size, void* d_ws, size_t ws_size,
                              hipStream_t stream) {
  const float* u       = (const float*)d_in[0];
  const float* W_in    = (const float*)d_in[1];
  const float* conv_w  = (const float*)d_in[2];
  const float* conv_b  = (const float*)d_in[3];
  const float* dt_bias = (const float*)d_in[4];
  const float* A_log   = (const float*)d_in[5];
  const float* Dp      = (const float*)d_in[6];
  const float* norm_w  = (const float*)d_in[7];
  const float* W_out   = (const float*)d_in[8];
  float* out = (float*)d_out;

  char* w = (char*)d_ws;
  unsigned short* zx_h   = (unsigned short*)w;  w += (size_t)BL*DPROJ*2;    // 35.9 MB
  unsigned short* xBC_h  = (unsigned short*)w;  w += (size_t)BL*CONV_DIM*2; // 18.9 MB
  unsigned short* ypre_h = (unsigned short*)w;  w += (size_t)BL*D_INNER*2;  // 16.8 MB
  unsigned short* y_h    = (unsigned short*)w;  w += (size_t)BL*D_INNER*2;  // 16.8 MB
  unsigned short* u_h    = (unsigned short*)w;  w += (size_t)BL*D_MODEL*2;  //  8.4 MB
  unsigned short* Win_h  = (unsigned short*)w;  w += (size_t)NPAD*D_MODEL*2;//  9.4 MB
  unsigned short* Wout_h = (unsigned short*)w;  w += (size_t)D_MODEL*D_INNER*2; // 4.2 MB
  unsigned short* states = (unsigned short*)w;  w += (size_t)B_SZ*NCHUNK*NHEADS*HEADDIM*D_STATE*2; // 33.5 MB
  float* dt     = (float*)w;  w += (size_t)BL*NHEADS*4;
  float* A_cum  = (float*)w;  w += (size_t)B_SZ*NHEADS*NCHUNK*CHUNK*4;
  float* G      = (float*)w;  w += (size_t)B_SZ*NCHUNK*CHUNK*CHUNK*4;

  cvt_f16<<<(BL*D_MODEL/4)/256, 256, 0, stream>>>(u, u_h, BL*D_MODEL/4);
  cvt_pad<<<((NPAD*D_MODEL/4)+255)/256, 256, 0, stream>>>(W_in, Win_h, DPROJ, NPAD*D_MODEL/4, D_MODEL/4);
  cvt_f16<<<(D_MODEL*D_INNER/4)/256, 256, 0, stream>>>(W_out, Wout_h, D_MODEL*D_INNER/4);
  // 1) zxbcdt = u @ W_in.T  (fp16 out; 256x256 8-wave kernel; grid 18x16=288, %8==0)
  gemm_f16_256<1><<<dim3(NPAD/256, BL/256), 512, 0, stream>>>(u_h, Win_h, zx_h, DPROJ, D_MODEL);
  // 2) dt = softplus(logits + bias) from GEMM1 output
  dtx_kernel<<<(BL*NHEADS+255)/256, 256, 0, stream>>>(zx_h, dt_bias, dt);
  // 3) per-chunk cumsum of A*dt
  acum_kernel<<<B_SZ*NHEADS*NCHUNK, 64, 0, stream>>>(dt, A_log, A_cum);
  // 4) depthwise conv + silu (fp16 in/out)
  conv8_kernel<<<((BL/8)*(CONV_DIM/4)+255)/256, 256, 0, stream>>>(zx_h, conv_w, conv_b, xBC_h);
  // 5) G = C B^T per (b,c)
  g_kernel<<<B_SZ*NCHUNK*4, 256, 0, stream>>>(xBC_h, G);
  // 6) per-chunk states (MFMA, fp16 out)
  states_mfma<<<B_SZ*NCHUNK*NHEADS, 256, 0, stream>>>(xBC_h, dt, A_cum, states);
  // 7) inter-chunk scan, 8-way split (fp16 storage)
  scan_kernel<<<B_SZ*NHEADS*8, 256, 0, stream>>>(A_cum, states);
  // 8) Y (MFMA), fp16 out
  y_mfma<<<B_SZ*NCHUNK*NHEADS, 256, 0, stream>>>(xBC_h, zx_h, dt, A_cum, G, states, Dp, ypre_h);
  // 9) RMS norm fp16->fp16
  rms_kernel<<<BL, 256, 0, stream>>>(ypre_h, norm_w, y_h);
  // 10) out = y @ W_out.T (fp32 out; 128x128 kernel, grid 8x32=256 covers the chip)
  gemm_f16_pipe<0><<<dim3(D_MODEL/128, BL/128), 256, 0, stream>>>(y_h, Wout_h, out, D_MODEL, D_INNER);
}

// Round 12
// 207.958 us; speedup vs baseline: 1.0351x; 1.0351x over previous
//
#include <hip/hip_runtime.h>
#include <hip/hip_bf16.h>
#include <math.h>

#define D_MODEL 1024
#define D_INNER 2048
#define D_STATE 128
#define NHEADS 32
#define HEADDIM 64
#define CHUNK 64
#define B_SZ 2
#define LSEQ 2048
#define BL (B_SZ*LSEQ)                              // 4096
#define DPROJ (2*D_INNER + 2*D_STATE + NHEADS)      // 4384
#define CONV_DIM (D_INNER + 2*D_STATE)              // 2304
#define NCHUNK (LSEQ/CHUNK)                         // 32
#define NPAD1 4480                                  // DPROJ padded to x128
#define EPSF 1e-5f

typedef __attribute__((ext_vector_type(8))) _Float16 half8;
typedef __attribute__((ext_vector_type(4))) _Float16 half4;
typedef __attribute__((ext_vector_type(4))) float f32x4;

__device__ __forceinline__ float siluf(float v){ return v / (1.0f + expf(-v)); }
__device__ __forceinline__ float softplusf(float v){ return v > 20.0f ? v : log1pf(expf(v)); }
__device__ __forceinline__ unsigned short f2h(float x){
  union { _Float16 h; unsigned short u; } v; v.h = (_Float16)x;
  return v.u;
}
__device__ __forceinline__ float h2f(unsigned short x){
  union { unsigned short u; _Float16 h; } v; v.u = x;
  return (float)v.h;
}
__device__ __forceinline__ _Float16 h2h(unsigned short x){
  union { unsigned short u; _Float16 h; } v; v.u = x;
  return v.h;
}

typedef const __attribute__((address_space(1))) void gvoid_t;
typedef __attribute__((address_space(3))) void lvoid_t;
__device__ __forceinline__ void gl_lds16(const void* gsrc, void* ldst) {
  gvoid_t* g = reinterpret_cast<gvoid_t*>((uintptr_t)gsrc);
  lvoid_t* l = reinterpret_cast<lvoid_t*>((unsigned int)(uintptr_t)ldst);
  __builtin_amdgcn_global_load_lds(g, l, 16, 0, 0);
}

#define NU4  (BL*D_MODEL/4)                         // 1,048,576
#define NW4  (NPAD1*D_MODEL/4)                      // 1,146,880
#define NWo4 (D_MODEL*D_INNER/4)                    //   524,288
#define NCVT (NU4+NW4+NWo4)

// ---------- fused converters: u -> fp16, W_in -> fp16 (padded), W_out*norm_w -> fp16 ----------
__global__ void cvt_all(const float* __restrict__ u, const float* __restrict__ W_in,
                        const float* __restrict__ W_out, const float* __restrict__ norm_w,
                        unsigned short* __restrict__ u_h, unsigned short* __restrict__ Win_h,
                        unsigned short* __restrict__ Wg_h) {
  int i = blockIdx.x*256 + threadIdx.x;
  if (i >= NCVT) return;
  if (i < NU4) {
    float4 v = *(const float4*)(u + (size_t)i*4);
    ushort4 o; o.x=f2h(v.x); o.y=f2h(v.y); o.z=f2h(v.z); o.w=f2h(v.w);
    *(ushort4*)(u_h + (size_t)i*4) = o;
  } else if (i < NU4 + NW4) {
    int q = i - NU4;
    int row = q / (D_MODEL/4);
    ushort4 o; o.x=0; o.y=0; o.z=0; o.w=0;
    if (row < DPROJ) {
      float4 v = *(const float4*)(W_in + (size_t)q*4);
      o.x=f2h(v.x); o.y=f2h(v.y); o.z=f2h(v.z); o.w=f2h(v.w);
    }
    *(ushort4*)(Win_h + (size_t)q*4) = o;
  } else {
    int q = i - NU4 - NW4;
    int colq = q % (D_INNER/4);
    float4 v = *(const float4*)(W_out + (size_t)q*4);
    float4 g = *(const float4*)(norm_w + (size_t)colq*4);
    ushort4 o; o.x=f2h(v.x*g.x); o.y=f2h(v.y*g.y); o.z=f2h(v.z*g.z); o.w=f2h(v.w*g.w);
    *(ushort4*)(Wg_h + (size_t)q*4) = o;
  }
}

// ---------- pipelined fp16 MFMA GEMM; 4 slots, prefetch depth 3 (round-8 best) ----------
// OUT_F16==1: fp16 C.  OUT_F16==0: fp32 C scaled by Sc[row] (RMS fold for GEMM2).
template<int OUT_F16>
__global__ __launch_bounds__(256) void gemm_f16_pipe(const unsigned short* __restrict__ A,
    const unsigned short* __restrict__ W, void* __restrict__ Cv,
    const float* __restrict__ Sc, int N, int K) {
  __shared__ unsigned short lds[4*2*4096];          // 64 KB -> 2 blocks/CU
  const int t   = threadIdx.x;
  const int wid = t >> 6, l = t & 63;
  const int nwg = gridDim.x * gridDim.y;
  int bid = blockIdx.y * gridDim.x + blockIdx.x;
  int swz = (bid & 7) * (nwg >> 3) + (bid >> 3);    // XCD-chunked (nwg%8==0)
  const int m0 = (swz / gridDim.x) * 128;
  const int n0 = (swz % gridDim.x) * 128;
  const int wr = wid >> 1, wc = wid & 1;
  const int fr = l & 15, cg = l >> 4;
  const int NT = K >> 5;

  int srow[2]; int scol[2];
  #pragma unroll
  for (int i=0;i<2;++i){
    int s = i*256 + t;
    int r = s >> 2, c = s & 3;
    int sw = (r + (r>>2)) & 3;
    srow[i] = r; scol[i] = (c ^ sw) * 8;
  }
  const unsigned short* Abase = A + (size_t)m0 * K;
  const unsigned short* Wbase = W + (size_t)n0 * K;

#define STAGE(tt, slot) { \
    int kk = (tt) << 5; \
    unsigned short* La = &lds[(slot)*8192]; \
    unsigned short* Lb = &lds[(slot)*8192 + 4096]; \
    gl_lds16(Abase + (size_t)srow[0]*K + kk + scol[0], (char*)La + (0*256+t)*16); \
    gl_lds16(Abase + (size_t)srow[1]*K + kk + scol[1], (char*)La + (1*256+t)*16); \
    gl_lds16(Wbase + (size_t)srow[0]*K + kk + scol[0], (char*)Lb + (0*256+t)*16); \
    gl_lds16(Wbase + (size_t)srow[1]*K + kk + scol[1], (char*)Lb + (1*256+t)*16); \
  }

  f32x4 acc[4][4] = {};
  STAGE(0, 0);
  STAGE(1, 1);
  STAGE(2, 2);
  asm volatile("s_waitcnt vmcnt(8)" ::: "memory");
  __builtin_amdgcn_s_barrier();
  asm volatile("" ::: "memory");

  for (int tt = 0; tt < NT; ++tt) {
    int slot = tt & 3;
    if (tt + 3 < NT) STAGE(tt+3, (tt+3)&3);
    const unsigned short* La = &lds[slot*8192];
    const unsigned short* Lb = &lds[slot*8192 + 4096];
    half8 af[4], bfv[4];
    #pragma unroll
    for (int m=0;m<4;++m){
      int r = wr*64 + m*16 + fr;
      int sw = (r + (r>>2)) & 3;
      af[m] = *(const half8*)&La[(r*4 + (cg ^ sw))*8];
    }
    #pragma unroll
    for (int n=0;n<4;++n){
      int r = wc*64 + n*16 + fr;
      int sw = (r + (r>>2)) & 3;
      bfv[n] = *(const half8*)&Lb[(r*4 + (cg ^ sw))*8];
    }
    __builtin_amdgcn_s_setprio(1);
    #pragma unroll
    for (int m=0;m<4;++m)
      #pragma unroll
      for (int n=0;n<4;++n)
        acc[m][n] = __builtin_amdgcn_mfma_f32_16x16x32_f16(af[m], bfv[n], acc[m][n], 0, 0, 0);
    __builtin_amdgcn_s_setprio(0);
    if (tt + 1 < NT) {
      if      (tt + 3 < NT) { asm volatile("s_waitcnt vmcnt(8)" ::: "memory"); }
      else if (tt + 2 < NT) { asm volatile("s_waitcnt vmcnt(4)" ::: "memory"); }
      else                  { asm volatile("s_waitcnt vmcnt(0)" ::: "memory"); }
      __builtin_amdgcn_s_barrier();
      asm volatile("" ::: "memory");
    }
  }
#undef STAGE

  const int crow = m0 + wr*64 + (l >> 4) * 4;
  const int ccol0 = n0 + wc*64 + fr;
  #pragma unroll
  for (int m = 0; m < 4; ++m) {
    #pragma unroll
    for (int n = 0; n < 4; ++n) {
      int col = ccol0 + n*16;
      if (col < N) {
        if (OUT_F16) {
          unsigned short* cp = (unsigned short*)Cv + (size_t)(crow + m*16)*N + col;
          #pragma unroll
          for (int j = 0; j < 4; ++j) cp[(size_t)j*N] = f2h(acc[m][n][j]);
        } else {
          float* cp = (float*)Cv + (size_t)(crow + m*16)*N + col;
          #pragma unroll
          for (int j = 0; j < 4; ++j) cp[(size_t)j*N] = acc[m][n][j] * Sc[crow + m*16 + j];
        }
      }
    }
  }
}

// ---------- fused dt + per-chunk cumsum ----------
__global__ __launch_bounds__(64) void dtacum_kernel(const unsigned short* __restrict__ zx,
    const float* __restrict__ dt_bias, const float* __restrict__ A_log,
    float* __restrict__ dt, float* __restrict__ A_cum) {
  int blk = blockIdx.x;                             // (b*32+h)*32+c
  int c = blk & 31, h = (blk >> 5) & 31, b = blk >> 10;
  int l = threadIdx.x;
  int row = b*LSEQ + c*CHUNK + l;
  float v = h2f(zx[(size_t)row*DPROJ + (2*D_INNER + 2*D_STATE) + h]) + dt_bias[h];
  float dtv = softplusf(v);
  dt[row*NHEADS + h] = dtv;
  float val = -expf(A_log[h]) * dtv;
  #pragma unroll
  for (int off = 1; off < 64; off <<= 1) {
    float nv = __shfl_up(val, off, 64);
    if (l >= off) val += nv;
  }
  A_cum[blk*64 + l] = val;
}

// causal depthwise conv (K=4) + bias + silu; fp16 in/out; 8 rows x 4 channels per thread
__global__ __launch_bounds__(256) void conv8_kernel(const unsigned short* __restrict__ zx,
    const float* __restrict__ w, const float* __restrict__ bias, unsigned short* __restrict__ xBC) {
  int idx = blockIdx.x*256 + threadIdx.x;           // over (BL/8) * (CONV_DIM/4)
  if (idx >= (BL/8)*(CONV_DIM/4)) return;
  int c4  = idx % (CONV_DIM/4);
  int rb  = idx / (CONV_DIM/4);
  int ch  = c4 * 4;
  int row0 = rb * 8;
  int l0   = row0 & (LSEQ-1);
  float4 r[11];
  #pragma unroll
  for (int jj=0;jj<11;++jj){
    int li = l0 + jj - 3;
    if (li >= 0) {
      ushort4 v = *(const ushort4*)&zx[(size_t)(row0 + jj - 3)*DPROJ + D_INNER + ch];
      r[jj] = make_float4(h2f(v.x), h2f(v.y), h2f(v.z), h2f(v.w));
    } else r[jj] = make_float4(0.f,0.f,0.f,0.f);
  }
  float4 wv[4];
  #pragma unroll
  for (int c=0;c<4;++c) wv[c] = *(const float4*)&w[(ch+c)*4];
  float4 bv = *(const float4*)&bias[ch];
  #pragma unroll
  for (int j=0;j<8;++j){
    float4 acc = bv;
    acc.x += wv[0].x*r[j].x + wv[0].y*r[j+1].x + wv[0].z*r[j+2].x + wv[0].w*r[j+3].x;
    acc.y += wv[1].x*r[j].y + wv[1].y*r[j+1].y + wv[1].z*r[j+2].y + wv[1].w*r[j+3].y;
    acc.z += wv[2].x*r[j].z + wv[2].y*r[j+1].z + wv[2].z*r[j+2].z + wv[2].w*r[j+3].z;
    acc.w += wv[3].x*r[j].w + wv[3].y*r[j+1].w + wv[3].z*r[j+2].w + wv[3].w*r[j+3].w;
    ushort4 o; o.x=f2h(siluf(acc.x)); o.y=f2h(siluf(acc.y)); o.z=f2h(siluf(acc.z)); o.w=f2h(siluf(acc.w));
    *(ushort4*)&xBC[(size_t)(row0+j)*CONV_DIM + ch] = o;
  }
}

// G[b,c][l][s] = sum_n C[l,n] * B[s,n]; 4 blocks per (b,c)
__global__ __launch_bounds__(256) void g_kernel(const unsigned short* __restrict__ xBC, float* __restrict__ G) {
  int blk = blockIdx.x >> 2;                        // b*32 + c
  int lq  = blockIdx.x & 3;
  int b = blk >> 5, c = blk & 31;
  __shared__ float Bsh[64][129];
  int t = threadIdx.x;
  int row0 = b*LSEQ + c*CHUNK;
  for (int j=0;j<32;++j){
    int lin = j*256 + t;
    int s = lin >> 7, n = lin & 127;
    Bsh[s][n] = h2f(xBC[(size_t)(row0+s)*CONV_DIM + D_INNER + n]);
  }
  __syncthreads();
  int l = lq*16 + (t >> 4), s0 = (t & 15) * 4;
  const unsigned short* Cp = &xBC[(size_t)(row0+l)*CONV_DIM + D_INNER + D_STATE];
  float acc[4] = {};
  for (int n=0;n<128;++n){
    float cv = h2f(Cp[n]);
    #pragma unroll
    for (int j=0;j<4;++j) acc[j] += cv * Bsh[s0+j][n];
  }
  float* Gp = &G[(size_t)blk*4096 + l*64 + s0];
  #pragma unroll
  for (int j=0;j<4;++j) Gp[j] = acc[j];
}

// ---------- MFMA states (fp16 out) ----------
__global__ __launch_bounds__(256) void states_mfma(const unsigned short* __restrict__ xBC,
    const float* __restrict__ dt, const float* __restrict__ A_cum, unsigned short* __restrict__ states) {
  int blk = blockIdx.x;                             // (b*32+c)*32+h
  int h = blk & 31, c = (blk>>5)&31, b = blk>>10;
  __shared__ _Float16 Bt[128][72];                  // [n][s]
  __shared__ _Float16 xdT[64][72];                  // [p][s]
  __shared__ float Ac[64], dtl[64];
  int t = threadIdx.x;
  int wid = t >> 6, ln = t & 63;
  int row0 = b*LSEQ + c*CHUNK;
  if (t < 64){ Ac[t] = A_cum[((b*32+h)*32 + c)*64 + t]; dtl[t] = dt[(row0+t)*NHEADS + h]; }
  __syncthreads();
  float AcL = Ac[63];
  #pragma unroll
  for (int j=0;j<32;++j){
    int lin = j*256+t; int s = lin>>7, n = lin&127;
    Bt[n][s] = h2h(xBC[(size_t)(row0+s)*CONV_DIM + D_INNER + n]);
  }
  #pragma unroll
  for (int j=0;j<16;++j){
    int lin = j*256+t; int s = lin>>6, p = lin&63;
    xdT[p][s] = (_Float16)(h2f(xBC[(size_t)(row0+s)*CONV_DIM + h*HEADDIM + p]) * dtl[s] * expf(AcL - Ac[s]));
  }
  __syncthreads();
  const int fr = ln & 15, fk = (ln >> 4) * 8;
  f32x4 acc[4][2] = {};
  #pragma unroll
  for (int ks = 0; ks < 2; ++ks){
    half8 a[4], bb[2];
    #pragma unroll
    for (int pt=0;pt<4;++pt) a[pt] = *(const half8*)&xdT[pt*16+fr][ks*32+fk];
    #pragma unroll
    for (int nt=0;nt<2;++nt) bb[nt] = *(const half8*)&Bt[(wid*2+nt)*16+fr][ks*32+fk];
    #pragma unroll
    for (int pt=0;pt<4;++pt)
      #pragma unroll
      for (int nt=0;nt<2;++nt)
        acc[pt][nt] = __builtin_amdgcn_mfma_f32_16x16x32_f16(a[pt], bb[nt], acc[pt][nt], 0, 0, 0);
  }
  unsigned short* Sp = &states[(size_t)blk*8192];
  #pragma unroll
  for (int pt=0;pt<4;++pt){
    int p0 = pt*16 + (ln>>4)*4;
    #pragma unroll
    for (int nt=0;nt<2;++nt){
      int n = (wid*2+nt)*16 + fr;
      #pragma unroll
      for (int j=0;j<4;++j) Sp[(p0+j)*128 + n] = f2h(acc[pt][nt][j]);
    }
  }
}

// inter-chunk scan (fp16 storage, fp32 accumulator), split 8-way
__global__ __launch_bounds__(256) void scan_kernel(const float* __restrict__ A_cum,
                                                   unsigned short* __restrict__ states) {
  int g  = blockIdx.x & 7;
  int bh = blockIdx.x >> 3;
  int b = bh >> 5, h = bh & 31;
  int t = threadIdx.x;
  float S[4];
  #pragma unroll
  for (int j=0;j<4;++j) S[j] = 0.f;
  for (int c=0;c<NCHUNK;++c){
    float decay = expf(A_cum[((b*32+h)*32 + c)*64 + 63]);
    unsigned short* Sp = &states[(size_t)((b*32+c)*32 + h)*8192];
    #pragma unroll
    for (int j=0;j<4;++j){
      float tmp = h2f(Sp[(g*4+j)*256+t]);
      Sp[(g*4+j)*256+t] = f2h(S[j]);
      S[j] = S[j]*decay + tmp;
    }
  }
}

// ---------- MFMA Y ----------
__global__ __launch_bounds__(256) void y_mfma(const unsigned short* __restrict__ xBC,
    const unsigned short* __restrict__ zx, const float* __restrict__ dt,
    const float* __restrict__ A_cum, const float* __restrict__ G,
    const unsigned short* __restrict__ states, const float* __restrict__ Dp,
    unsigned short* __restrict__ y_pre) {
  int blk = blockIdx.x;                             // (b*32+c)*32+h
  int h = blk & 31, c = (blk>>5)&31, b = blk>>10;
  __shared__ _Float16 Cl[64][136];
  __shared__ _Float16 Sin[64][136];
  __shared__ _Float16 Ms[64][72];
  __shared__ _Float16 xdT[64][72];
  __shared__ float Ac[64], dtl[64];
  int t = threadIdx.x;
  int wid = t >> 6, ln = t & 63;
  int row0 = b*LSEQ + c*CHUNK;
  if (t < 64){ Ac[t] = A_cum[((b*32+h)*32 + c)*64 + t]; dtl[t] = dt[(row0+t)*NHEADS + h]; }
  __syncthreads();
  #pragma unroll
  for (int j=0;j<32;++j){
    int lin = j*256+t; int l = lin>>7, n = lin&127;
    Cl[l][n] = (_Float16)(h2f(xBC[(size_t)(row0+l)*CONV_DIM + D_INNER + D_STATE + n]) * expf(Ac[l]));
  }
  {
    const unsigned short* Sg = &states[(size_t)blk*8192];
    #pragma unroll
    for (int j=0;j<8;++j){
      int elem = (j*256+t)*4; int p = elem>>7, n = elem&127;
      ushort4 v = *(const ushort4*)&Sg[elem];
      half4 hv = { h2h(v.x), h2h(v.y), h2h(v.z), h2h(v.w) };
      *(half4*)&Sin[p][n] = hv;
    }
  }
  #pragma unroll
  for (int j=0;j<16;++j){
    int lin = j*256+t; int s = lin>>6, p = lin&63;
    xdT[p][s] = (_Float16)(h2f(xBC[(size_t)(row0+s)*CONV_DIM + h*HEADDIM + p]) * dtl[s]);
  }
  {
    const float* Gp = &G[(size_t)(b*32+c)*4096];
    #pragma unroll
    for (int j=0;j<16;++j){
      int lin = j*256+t; int l = lin>>6, s = lin&63;
      Ms[l][s] = (s <= l) ? (_Float16)(Gp[l*64+s] * expf(Ac[l]-Ac[s])) : (_Float16)0.f;
    }
  }
  __syncthreads();
  const int wr = wid >> 1, wc = wid & 1;
  const int fr = ln & 15, fk = (ln >> 4) * 8;
  f32x4 acc[2][2] = {};
  #pragma unroll
  for (int ks = 0; ks < 4; ++ks){
    half8 a[2], bb[2];
    #pragma unroll
    for (int lt=0;lt<2;++lt) a[lt] = *(const half8*)&Cl[(wr*2+lt)*16+fr][ks*32+fk];
    #pragma unroll
    for (int pt=0;pt<2;++pt) bb[pt] = *(const half8*)&Sin[(wc*2+pt)*16+fr][ks*32+fk];
    #pragma unroll
    for (int lt=0;lt<2;++lt)
      #pragma unroll
      for (int pt=0;pt<2;++pt)
        acc[lt][pt] = __builtin_amdgcn_mfma_f32_16x16x32_f16(a[lt], bb[pt], acc[lt][pt], 0, 0, 0);
  }
  #pragma unroll
  for (int ks = 0; ks < 2; ++ks){
    half8 a[2], bb[2];
    #pragma unroll
    for (int lt=0;lt<2;++lt) a[lt] = *(const half8*)&Ms[(wr*2+lt)*16+fr][ks*32+fk];
    #pragma unroll
    for (int pt=0;pt<2;++pt) bb[pt] = *(const half8*)&xdT[(wc*2+pt)*16+fr][ks*32+fk];
    #pragma unroll
    for (int lt=0;lt<2;++lt)
      #pragma unroll
      for (int pt=0;pt<2;++pt)
        acc[lt][pt] = __builtin_amdgcn_mfma_f32_16x16x32_f16(a[lt], bb[pt], acc[lt][pt], 0, 0, 0);
  }
  float Dh = Dp[h];
  #pragma unroll
  for (int lt=0;lt<2;++lt){
    int l0 = (wr*2+lt)*16 + (ln>>4)*4;
    #pragma unroll
    for (int pt=0;pt<2;++pt){
      int p = (wc*2+pt)*16 + fr;
      #pragma unroll
      for (int j=0;j<4;++j){
        int grow = row0 + l0 + j;
        float x = h2f(xBC[(size_t)grow*CONV_DIM + h*HEADDIM + p]);
        float z = h2f(zx[(size_t)grow*DPROJ + h*HEADDIM + p]);
        y_pre[(size_t)grow*D_INNER + h*HEADDIM + p] = f2h((acc[lt][pt][j] + x*Dh) * siluf(z));
      }
    }
  }
}

// per-row RMS scale: sc[row] = rsqrt(mean(ypre^2) + eps)
__global__ __launch_bounds__(256) void rowsc_kernel(const unsigned short* __restrict__ y,
                                                    float* __restrict__ sc) {
  int row = blockIdx.x;
  int t = threadIdx.x;
  const unsigned short* yr = y + (size_t)row*D_INNER + t*8;
  ushort4 a = *(const ushort4*)yr;
  ushort4 bq = *(const ushort4*)(yr+4);
  float ss = 0.f;
  float v;
  v=h2f(a.x); ss+=v*v; v=h2f(a.y); ss+=v*v; v=h2f(a.z); ss+=v*v; v=h2f(a.w); ss+=v*v;
  v=h2f(bq.x); ss+=v*v; v=h2f(bq.y); ss+=v*v; v=h2f(bq.z); ss+=v*v; v=h2f(bq.w); ss+=v*v;
  #pragma unroll
  for (int off=32; off>0; off>>=1) ss += __shfl_down(ss, off, 64);
  __shared__ float wsum[4];
  int wid = t >> 6, lane = t & 63;
  if (lane == 0) wsum[wid] = ss;
  __syncthreads();
  if (t == 0) sc[row] = rsqrtf((wsum[0]+wsum[1]+wsum[2]+wsum[3])/D_INNER + EPSF);
}

extern "C" void kernel_launch(void* const* d_in, const int* in_sizes, int n_in,
                              void* d_out, int out_size, void* d_ws, size_t ws_size,
                              hipStream_t stream) {
  const float* u       = (const float*)d_in[0];
  const float* W_in    = (const float*)d_in[1];
  const float* conv_w  = (const float*)d_in[2];
  const float* conv_b  = (const float*)d_in[3];
  const float* dt_bias = (const float*)d_in[4];
  const float* A_log   = (const float*)d_in[5];
  const float* Dp      = (const float*)d_in[6];
  const float* norm_w  = (const float*)d_in[7];
  const float* W_out   = (const float*)d_in[8];
  float* out = (float*)d_out;

  char* w = (char*)d_ws;
  unsigned short* zx_h   = (unsigned short*)w;  w += (size_t)BL*DPROJ*2;    // 35.9 MB
  unsigned short* xBC_h  = (unsigned short*)w;  w += (size_t)BL*CONV_DIM*2; // 18.9 MB
  unsigned short* ypre_h = (unsigned short*)w;  w += (size_t)BL*D_INNER*2;  // 16.8 MB
  unsigned short* u_h    = (unsigned short*)w;  w += (size_t)BL*D_MODEL*2;  //  8.4 MB
  unsigned short* Win_h  = (unsigned short*)w;  w += (size_t)NPAD1*D_MODEL*2;// 9.2 MB
  unsigned short* Wg_h   = (unsigned short*)w;  w += (size_t)D_MODEL*D_INNER*2; // 4.2 MB
  unsigned short* states = (unsigned short*)w;  w += (size_t)B_SZ*NCHUNK*NHEADS*HEADDIM*D_STATE*2; // 33.5 MB
  float* dt     = (float*)w;  w += (size_t)BL*NHEADS*4;
  float* A_cum  = (float*)w;  w += (size_t)B_SZ*NHEADS*NCHUNK*CHUNK*4;
  float* G      = (float*)w;  w += (size_t)B_SZ*NCHUNK*CHUNK*CHUNK*4;
  float* sc     = (float*)w;  w += (size_t)BL*4;

  // 0) all converts in one launch (Wg = W_out * norm_w, RMS fold)
  cvt_all<<<(NCVT+255)/256, 256, 0, stream>>>(u, W_in, W_out, norm_w, u_h, Win_h, Wg_h);
  // 1) zxbcdt = u @ W_in.T  (fp16 out; includes dt logit columns)
  gemm_f16_pipe<1><<<dim3(NPAD1/128, BL/128), 256, 0, stream>>>(u_h, Win_h, zx_h, nullptr, DPROJ, D_MODEL);
  // 2) dt + per-chunk cumsum (fused, shfl prefix)
  dtacum_kernel<<<B_SZ*NHEADS*NCHUNK, 64, 0, stream>>>(zx_h, dt_bias, A_log, dt, A_cum);
  // 3) depthwise conv + silu (fp16 in/out)
  conv8_kernel<<<((BL/8)*(CONV_DIM/4)+255)/256, 256, 0, stream>>>(zx_h, conv_w, conv_b, xBC_h);
  // 4) G = C B^T per (b,c)
  g_kernel<<<B_SZ*NCHUNK*4, 256, 0, stream>>>(xBC_h, G);
  // 5) per-chunk states (MFMA, fp16 out)
  states_mfma<<<B_SZ*NCHUNK*NHEADS, 256, 0, stream>>>(xBC_h, dt, A_cum, states);
  // 6) inter-chunk scan, 8-way split (fp16 storage)
  scan_kernel<<<B_SZ*NHEADS*8, 256, 0, stream>>>(A_cum, states);
  // 7) Y (MFMA), fp16 out (unnormalized)
  y_mfma<<<B_SZ*NCHUNK*NHEADS, 256, 0, stream>>>(xBC_h, zx_h, dt, A_cum, G, states, Dp, ypre_h);
  // 8) per-row RMS scale
  rowsc_kernel<<<BL, 256, 0, stream>>>(ypre_h, sc);
  // 9) out = diag(sc) * (ypre @ (W_out*norm_w).T)  (fp32 out, scaled epilogue)
  gemm_f16_pipe<0><<<dim3(D_MODEL/128, BL/128), 256, 0, stream>>>(ypre_h, Wg_h, out, sc, D_MODEL, D_INNER);
}

// Round 13
// 199.461 us; speedup vs baseline: 1.0792x; 1.0426x over previous
//
#include <hip/hip_runtime.h>
#include <hip/hip_bf16.h>
#include <math.h>

#define D_MODEL 1024
#define D_INNER 2048
#define D_STATE 128
#define NHEADS 32
#define HEADDIM 64
#define CHUNK 64
#define B_SZ 2
#define LSEQ 2048
#define BL (B_SZ*LSEQ)                              // 4096
#define DPROJ (2*D_INNER + 2*D_STATE + NHEADS)      // 4384
#define CONV_DIM (D_INNER + 2*D_STATE)              // 2304
#define NCHUNK (LSEQ/CHUNK)                         // 32
#define NPAD1 4480                                  // DPROJ padded to x128
#define EPSF 1e-5f

typedef __attribute__((ext_vector_type(8))) _Float16 half8;
typedef __attribute__((ext_vector_type(4))) _Float16 half4;
typedef __attribute__((ext_vector_type(4))) float f32x4;

__device__ __forceinline__ float siluf(float v){ return v / (1.0f + expf(-v)); }
__device__ __forceinline__ float softplusf(float v){ return v > 20.0f ? v : log1pf(expf(v)); }
__device__ __forceinline__ unsigned short f2h(float x){
  union { _Float16 h; unsigned short u; } v; v.h = (_Float16)x;
  return v.u;
}
__device__ __forceinline__ float h2f(unsigned short x){
  union { unsigned short u; _Float16 h; } v; v.u = x;
  return (float)v.h;
}
__device__ __forceinline__ _Float16 h2h(unsigned short x){
  union { unsigned short u; _Float16 h; } v; v.u = x;
  return v.h;
}

typedef const __attribute__((address_space(1))) void gvoid_t;
typedef __attribute__((address_space(3))) void lvoid_t;
__device__ __forceinline__ void gl_lds16(const void* gsrc, void* ldst) {
  gvoid_t* g = reinterpret_cast<gvoid_t*>((uintptr_t)gsrc);
  lvoid_t* l = reinterpret_cast<lvoid_t*>((unsigned int)(uintptr_t)ldst);
  __builtin_amdgcn_global_load_lds(g, l, 16, 0, 0);
}

#define NU4  (BL*D_MODEL/4)
#define NW4  (NPAD1*D_MODEL/4)
#define NWo4 (D_MODEL*D_INNER/4)
#define NCVT (NU4+NW4+NWo4)

// ---------- fused converters ----------
__global__ void cvt_all(const float* __restrict__ u, const float* __restrict__ W_in,
                        const float* __restrict__ W_out, const float* __restrict__ norm_w,
                        unsigned short* __restrict__ u_h, unsigned short* __restrict__ Win_h,
                        unsigned short* __restrict__ Wg_h) {
  int i = blockIdx.x*256 + threadIdx.x;
  if (i >= NCVT) return;
  if (i < NU4) {
    float4 v = *(const float4*)(u + (size_t)i*4);
    ushort4 o; o.x=f2h(v.x); o.y=f2h(v.y); o.z=f2h(v.z); o.w=f2h(v.w);
    *(ushort4*)(u_h + (size_t)i*4) = o;
  } else if (i < NU4 + NW4) {
    int q = i - NU4;
    int row = q / (D_MODEL/4);
    ushort4 o; o.x=0; o.y=0; o.z=0; o.w=0;
    if (row < DPROJ) {
      float4 v = *(const float4*)(W_in + (size_t)q*4);
      o.x=f2h(v.x); o.y=f2h(v.y); o.z=f2h(v.z); o.w=f2h(v.w);
    }
    *(ushort4*)(Win_h + (size_t)q*4) = o;
  } else {
    int q = i - NU4 - NW4;
    int colq = q % (D_INNER/4);
    float4 v = *(const float4*)(W_out + (size_t)q*4);
    float4 g = *(const float4*)(norm_w + (size_t)colq*4);
    ushort4 o; o.x=f2h(v.x*g.x); o.y=f2h(v.y*g.y); o.z=f2h(v.z*g.z); o.w=f2h(v.w*g.w);
    *(ushort4*)(Wg_h + (size_t)q*4) = o;
  }
}

// ---------- pipelined fp16 MFMA GEMM; 4 slots, prefetch depth 3 (round-8 best) ----------
template<int OUT_F16>
__global__ __launch_bounds__(256) void gemm_f16_pipe(const unsigned short* __restrict__ A,
    const unsigned short* __restrict__ W, void* __restrict__ Cv,
    const float* __restrict__ Sc, int N, int K) {
  __shared__ unsigned short lds[4*2*4096];          // 64 KB -> 2 blocks/CU
  const int t   = threadIdx.x;
  const int wid = t >> 6, l = t & 63;
  const int nwg = gridDim.x * gridDim.y;
  int bid = blockIdx.y * gridDim.x + blockIdx.x;
  int swz = (bid & 7) * (nwg >> 3) + (bid >> 3);    // XCD-chunked (nwg%8==0)
  const int m0 = (swz / gridDim.x) * 128;
  const int n0 = (swz % gridDim.x) * 128;
  const int wr = wid >> 1, wc = wid & 1;
  const int fr = l & 15, cg = l >> 4;
  const int NT = K >> 5;

  int srow[2]; int scol[2];
  #pragma unroll
  for (int i=0;i<2;++i){
    int s = i*256 + t;
    int r = s >> 2, c = s & 3;
    int sw = (r + (r>>2)) & 3;
    srow[i] = r; scol[i] = (c ^ sw) * 8;
  }
  const unsigned short* Abase = A + (size_t)m0 * K;
  const unsigned short* Wbase = W + (size_t)n0 * K;

#define STAGE(tt, slot) { \
    int kk = (tt) << 5; \
    unsigned short* La = &lds[(slot)*8192]; \
    unsigned short* Lb = &lds[(slot)*8192 + 4096]; \
    gl_lds16(Abase + (size_t)srow[0]*K + kk + scol[0], (char*)La + (0*256+t)*16); \
    gl_lds16(Abase + (size_t)srow[1]*K + kk + scol[1], (char*)La + (1*256+t)*16); \
    gl_lds16(Wbase + (size_t)srow[0]*K + kk + scol[0], (char*)Lb + (0*256+t)*16); \
    gl_lds16(Wbase + (size_t)srow[1]*K + kk + scol[1], (char*)Lb + (1*256+t)*16); \
  }

  f32x4 acc[4][4] = {};
  STAGE(0, 0);
  STAGE(1, 1);
  STAGE(2, 2);
  asm volatile("s_waitcnt vmcnt(8)" ::: "memory");
  __builtin_amdgcn_s_barrier();
  asm volatile("" ::: "memory");

  for (int tt = 0; tt < NT; ++tt) {
    int slot = tt & 3;
    if (tt + 3 < NT) STAGE(tt+3, (tt+3)&3);
    const unsigned short* La = &lds[slot*8192];
    const unsigned short* Lb = &lds[slot*8192 + 4096];
    half8 af[4], bfv[4];
    #pragma unroll
    for (int m=0;m<4;++m){
      int r = wr*64 + m*16 + fr;
      int sw = (r + (r>>2)) & 3;
      af[m] = *(const half8*)&La[(r*4 + (cg ^ sw))*8];
    }
    #pragma unroll
    for (int n=0;n<4;++n){
      int r = wc*64 + n*16 + fr;
      int sw = (r + (r>>2)) & 3;
      bfv[n] = *(const half8*)&Lb[(r*4 + (cg ^ sw))*8];
    }
    __builtin_amdgcn_s_setprio(1);
    #pragma unroll
    for (int m=0;m<4;++m)
      #pragma unroll
      for (int n=0;n<4;++n)
        acc[m][n] = __builtin_amdgcn_mfma_f32_16x16x32_f16(af[m], bfv[n], acc[m][n], 0, 0, 0);
    __builtin_amdgcn_s_setprio(0);
    if (tt + 1 < NT) {
      if      (tt + 3 < NT) { asm volatile("s_waitcnt vmcnt(8)" ::: "memory"); }
      else if (tt + 2 < NT) { asm volatile("s_waitcnt vmcnt(4)" ::: "memory"); }
      else                  { asm volatile("s_waitcnt vmcnt(0)" ::: "memory"); }
      __builtin_amdgcn_s_barrier();
      asm volatile("" ::: "memory");
    }
  }
#undef STAGE

  const int crow = m0 + wr*64 + (l >> 4) * 4;
  const int ccol0 = n0 + wc*64 + fr;
  #pragma unroll
  for (int m = 0; m < 4; ++m) {
    #pragma unroll
    for (int n = 0; n < 4; ++n) {
      int col = ccol0 + n*16;
      if (col < N) {
        if (OUT_F16) {
          unsigned short* cp = (unsigned short*)Cv + (size_t)(crow + m*16)*N + col;
          #pragma unroll
          for (int j = 0; j < 4; ++j) cp[(size_t)j*N] = f2h(acc[m][n][j]);
        } else {
          float* cp = (float*)Cv + (size_t)(crow + m*16)*N + col;
          #pragma unroll
          for (int j = 0; j < 4; ++j) cp[(size_t)j*N] = acc[m][n][j] * Sc[crow + m*16 + j];
        }
      }
    }
  }
}

// ---------- fused dt + per-chunk cumsum ----------
__global__ __launch_bounds__(64) void dtacum_kernel(const unsigned short* __restrict__ zx,
    const float* __restrict__ dt_bias, const float* __restrict__ A_log,
    float* __restrict__ dt, float* __restrict__ A_cum) {
  int blk = blockIdx.x;                             // (b*32+h)*32+c
  int c = blk & 31, h = (blk >> 5) & 31, b = blk >> 10;
  int l = threadIdx.x;
  int row = b*LSEQ + c*CHUNK + l;
  float v = h2f(zx[(size_t)row*DPROJ + (2*D_INNER + 2*D_STATE) + h]) + dt_bias[h];
  float dtv = softplusf(v);
  dt[row*NHEADS + h] = dtv;
  float val = -expf(A_log[h]) * dtv;
  #pragma unroll
  for (int off = 1; off < 64; off <<= 1) {
    float nv = __shfl_up(val, off, 64);
    if (l >= off) val += nv;
  }
  A_cum[blk*64 + l] = val;
}

// causal depthwise conv (K=4) + bias + silu; fp16 in/out; 8 rows x 4 channels per thread
__global__ __launch_bounds__(256) void conv8_kernel(const unsigned short* __restrict__ zx,
    const float* __restrict__ w, const float* __restrict__ bias, unsigned short* __restrict__ xBC) {
  int idx = blockIdx.x*256 + threadIdx.x;           // over (BL/8) * (CONV_DIM/4)
  if (idx >= (BL/8)*(CONV_DIM/4)) return;
  int c4  = idx % (CONV_DIM/4);
  int rb  = idx / (CONV_DIM/4);
  int ch  = c4 * 4;
  int row0 = rb * 8;
  int l0   = row0 & (LSEQ-1);
  float4 r[11];
  #pragma unroll
  for (int jj=0;jj<11;++jj){
    int li = l0 + jj - 3;
    if (li >= 0) {
      ushort4 v = *(const ushort4*)&zx[(size_t)(row0 + jj - 3)*DPROJ + D_INNER + ch];
      r[jj] = make_float4(h2f(v.x), h2f(v.y), h2f(v.z), h2f(v.w));
    } else r[jj] = make_float4(0.f,0.f,0.f,0.f);
  }
  float4 wv[4];
  #pragma unroll
  for (int c=0;c<4;++c) wv[c] = *(const float4*)&w[(ch+c)*4];
  float4 bv = *(const float4*)&bias[ch];
  #pragma unroll
  for (int j=0;j<8;++j){
    float4 acc = bv;
    acc.x += wv[0].x*r[j].x + wv[0].y*r[j+1].x + wv[0].z*r[j+2].x + wv[0].w*r[j+3].x;
    acc.y += wv[1].x*r[j].y + wv[1].y*r[j+1].y + wv[1].z*r[j+2].y + wv[1].w*r[j+3].y;
    acc.z += wv[2].x*r[j].z + wv[2].y*r[j+1].z + wv[2].z*r[j+2].z + wv[2].w*r[j+3].z;
    acc.w += wv[3].x*r[j].w + wv[3].y*r[j+1].w + wv[3].z*r[j+2].w + wv[3].w*r[j+3].w;
    ushort4 o; o.x=f2h(siluf(acc.x)); o.y=f2h(siluf(acc.y)); o.z=f2h(siluf(acc.z)); o.w=f2h(siluf(acc.w));
    *(ushort4*)&xBC[(size_t)(row0+j)*CONV_DIM + ch] = o;
  }
}

// G[b,c][l][s] = sum_n C[l,n] * B[s,n]; 4 blocks per (b,c); fp16 G out
__global__ __launch_bounds__(256) void g_kernel(const unsigned short* __restrict__ xBC,
                                                unsigned short* __restrict__ G) {
  int blk = blockIdx.x >> 2;                        // b*32 + c
  int lq  = blockIdx.x & 3;
  int b = blk >> 5, c = blk & 31;
  __shared__ float Bsh[64][129];
  int t = threadIdx.x;
  int row0 = b*LSEQ + c*CHUNK;
  #pragma unroll
  for (int j=0;j<8;++j){
    int e0 = (j*256 + t)*4;                         // 0..8191
    int s = e0 >> 7, n = e0 & 127;
    ushort4 v = *(const ushort4*)&xBC[(size_t)(row0+s)*CONV_DIM + D_INNER + n];
    Bsh[s][n+0] = h2f(v.x); Bsh[s][n+1] = h2f(v.y);
    Bsh[s][n+2] = h2f(v.z); Bsh[s][n+3] = h2f(v.w);
  }
  __syncthreads();
  int l = lq*16 + (t >> 4), s0 = (t & 15) * 4;
  const unsigned short* Cp = &xBC[(size_t)(row0+l)*CONV_DIM + D_INNER + D_STATE];
  float acc[4] = {};
  #pragma unroll 4
  for (int n4=0;n4<32;++n4){
    ushort4 cv4 = *(const ushort4*)&Cp[n4*4];
    float cv[4] = { h2f(cv4.x), h2f(cv4.y), h2f(cv4.z), h2f(cv4.w) };
    #pragma unroll
    for (int k=0;k<4;++k){
      #pragma unroll
      for (int j=0;j<4;++j) acc[j] += cv[k] * Bsh[s0+j][n4*4+k];
    }
  }
  unsigned short* Gp = &G[(size_t)blk*4096 + l*64 + s0];
  ushort4 o; o.x=f2h(acc[0]); o.y=f2h(acc[1]); o.z=f2h(acc[2]); o.w=f2h(acc[3]);
  *(ushort4*)Gp = o;
}

// ---------- MFMA states (fp16 out, vectorized staging) ----------
__global__ __launch_bounds__(256) void states_mfma(const unsigned short* __restrict__ xBC,
    const float* __restrict__ dt, const float* __restrict__ A_cum, unsigned short* __restrict__ states) {
  int blk = blockIdx.x;                             // (b*32+c)*32+h
  int h = blk & 31, c = (blk>>5)&31, b = blk>>10;
  __shared__ _Float16 Bt[128][72];                  // [n][s]
  __shared__ _Float16 xdT[64][72];                  // [p][s]
  __shared__ float Ac[64], dtl[64];
  int t = threadIdx.x;
  int wid = t >> 6, ln = t & 63;
  int row0 = b*LSEQ + c*CHUNK;
  if (t < 64){ Ac[t] = A_cum[((b*32+h)*32 + c)*64 + t]; dtl[t] = dt[(row0+t)*NHEADS + h]; }
  __syncthreads();
  float AcL = Ac[63];
  #pragma unroll
  for (int j=0;j<8;++j){
    int e0 = (j*256+t)*4;                           // 0..8191
    int s = e0 >> 7, n = e0 & 127;
    ushort4 v = *(const ushort4*)&xBC[(size_t)(row0+s)*CONV_DIM + D_INNER + n];
    Bt[n+0][s] = h2h(v.x); Bt[n+1][s] = h2h(v.y);
    Bt[n+2][s] = h2h(v.z); Bt[n+3][s] = h2h(v.w);
  }
  #pragma unroll
  for (int j=0;j<4;++j){
    int e0 = (j*256+t)*4;                           // 0..4095
    int s = e0 >> 6, p = e0 & 63;
    float sc = dtl[s] * expf(AcL - Ac[s]);
    ushort4 v = *(const ushort4*)&xBC[(size_t)(row0+s)*CONV_DIM + h*HEADDIM + p];
    xdT[p+0][s] = (_Float16)(h2f(v.x)*sc);
    xdT[p+1][s] = (_Float16)(h2f(v.y)*sc);
    xdT[p+2][s] = (_Float16)(h2f(v.z)*sc);
    xdT[p+3][s] = (_Float16)(h2f(v.w)*sc);
  }
  __syncthreads();
  const int fr = ln & 15, fk = (ln >> 4) * 8;
  f32x4 acc[4][2] = {};
  #pragma unroll
  for (int ks = 0; ks < 2; ++ks){
    half8 a[4], bb[2];
    #pragma unroll
    for (int pt=0;pt<4;++pt) a[pt] = *(const half8*)&xdT[pt*16+fr][ks*32+fk];
    #pragma unroll
    for (int nt=0;nt<2;++nt) bb[nt] = *(const half8*)&Bt[(wid*2+nt)*16+fr][ks*32+fk];
    #pragma unroll
    for (int pt=0;pt<4;++pt)
      #pragma unroll
      for (int nt=0;nt<2;++nt)
        acc[pt][nt] = __builtin_amdgcn_mfma_f32_16x16x32_f16(a[pt], bb[nt], acc[pt][nt], 0, 0, 0);
  }
  unsigned short* Sp = &states[(size_t)blk*8192];
  #pragma unroll
  for (int pt=0;pt<4;++pt){
    int p0 = pt*16 + (ln>>4)*4;
    #pragma unroll
    for (int nt=0;nt<2;++nt){
      int n = (wid*2+nt)*16 + fr;
      #pragma unroll
      for (int j=0;j<4;++j) Sp[(p0+j)*128 + n] = f2h(acc[pt][nt][j]);
    }
  }
}

// inter-chunk scan: prefetch all chunk values, then serial VALU recurrence + stores
__global__ __launch_bounds__(256) void scan_kernel(const float* __restrict__ A_cum,
                                                   unsigned short* __restrict__ states) {
  int g  = blockIdx.x & 7;
  int bh = blockIdx.x >> 3;
  int b = bh >> 5, h = bh & 31;
  int t = threadIdx.x;
  int off = g*1024 + t*4;
  ushort4 tmp[NCHUNK];
  float dec[NCHUNK];
  #pragma unroll
  for (int c=0;c<NCHUNK;++c){
    tmp[c] = *(const ushort4*)&states[(size_t)((b*32+c)*32 + h)*8192 + off];
    dec[c] = A_cum[((b*32+h)*32 + c)*64 + 63];
  }
  float s0=0.f, s1=0.f, s2=0.f, s3=0.f;
  #pragma unroll
  for (int c=0;c<NCHUNK;++c){
    float d = expf(dec[c]);
    ushort4 o; o.x=f2h(s0); o.y=f2h(s1); o.z=f2h(s2); o.w=f2h(s3);
    *(ushort4*)&states[(size_t)((b*32+c)*32 + h)*8192 + off] = o;
    s0 = s0*d + h2f(tmp[c].x);
    s1 = s1*d + h2f(tmp[c].y);
    s2 = s2*d + h2f(tmp[c].z);
    s3 = s3*d + h2f(tmp[c].w);
  }
}

// ---------- MFMA Y (vectorized staging, fp16 G) ----------
__global__ __launch_bounds__(256) void y_mfma(const unsigned short* __restrict__ xBC,
    const unsigned short* __restrict__ zx, const float* __restrict__ dt,
    const float* __restrict__ A_cum, const unsigned short* __restrict__ G,
    const unsigned short* __restrict__ states, const float* __restrict__ Dp,
    unsigned short* __restrict__ y_pre) {
  int blk = blockIdx.x;                             // (b*32+c)*32+h
  int h = blk & 31, c = (blk>>5)&31, b = blk>>10;
  __shared__ _Float16 Cl[64][136];
  __shared__ _Float16 Sin[64][136];
  __shared__ _Float16 Ms[64][72];
  __shared__ _Float16 xdT[64][72];
  __shared__ float Ac[64], dtl[64];
  int t = threadIdx.x;
  int wid = t >> 6, ln = t & 63;
  int row0 = b*LSEQ + c*CHUNK;
  if (t < 64){ Ac[t] = A_cum[((b*32+h)*32 + c)*64 + t]; dtl[t] = dt[(row0+t)*NHEADS + h]; }
  __syncthreads();
  #pragma unroll
  for (int j=0;j<8;++j){
    int e0 = (j*256+t)*4; int l = e0>>7, n = e0&127;
    float sc = expf(Ac[l]);
    ushort4 v = *(const ushort4*)&xBC[(size_t)(row0+l)*CONV_DIM + D_INNER + D_STATE + n];
    half4 hv = { (_Float16)(h2f(v.x)*sc), (_Float16)(h2f(v.y)*sc),
                 (_Float16)(h2f(v.z)*sc), (_Float16)(h2f(v.w)*sc) };
    *(half4*)&Cl[l][n] = hv;
  }
  {
    const unsigned short* Sg = &states[(size_t)blk*8192];
    #pragma unroll
    for (int j=0;j<8;++j){
      int elem = (j*256+t)*4; int p = elem>>7, n = elem&127;
      ushort4 v = *(const ushort4*)&Sg[elem];
      half4 hv = { h2h(v.x), h2h(v.y), h2h(v.z), h2h(v.w) };
      *(half4*)&Sin[p][n] = hv;
    }
  }
  #pragma unroll
  for (int j=0;j<4;++j){
    int e0 = (j*256+t)*4; int s = e0>>6, p = e0&63;
    float sc = dtl[s];
    ushort4 v = *(const ushort4*)&xBC[(size_t)(row0+s)*CONV_DIM + h*HEADDIM + p];
    xdT[p+0][s] = (_Float16)(h2f(v.x)*sc);
    xdT[p+1][s] = (_Float16)(h2f(v.y)*sc);
    xdT[p+2][s] = (_Float16)(h2f(v.z)*sc);
    xdT[p+3][s] = (_Float16)(h2f(v.w)*sc);
  }
  {
    const unsigned short* Gp = &G[(size_t)(b*32+c)*4096];
    #pragma unroll
    for (int j=0;j<4;++j){
      int e0 = (j*256+t)*4; int l = e0>>6, s = e0&63;
      ushort4 gv = *(const ushort4*)&Gp[e0];
      float al = Ac[l];
      Ms[l][s+0] = (s+0 <= l) ? (_Float16)(h2f(gv.x) * expf(al-Ac[s+0])) : (_Float16)0.f;
      Ms[l][s+1] = (s+1 <= l) ? (_Float16)(h2f(gv.y) * expf(al-Ac[s+1])) : (_Float16)0.f;
      Ms[l][s+2] = (s+2 <= l) ? (_Float16)(h2f(gv.z) * expf(al-Ac[s+2])) : (_Float16)0.f;
      Ms[l][s+3] = (s+3 <= l) ? (_Float16)(h2f(gv.w) * expf(al-Ac[s+3])) : (_Float16)0.f;
    }
  }
  __syncthreads();
  const int wr = wid >> 1, wc = wid & 1;
  const int fr = ln & 15, fk = (ln >> 4) * 8;
  f32x4 acc[2][2] = {};
  #pragma unroll
  for (int ks = 0; ks < 4; ++ks){
    half8 a[2], bb[2];
    #pragma unroll
    for (int lt=0;lt<2;++lt) a[lt] = *(const half8*)&Cl[(wr*2+lt)*16+fr][ks*32+fk];
    #pragma unroll
    for (int pt=0;pt<2;++pt) bb[pt] = *(const half8*)&Sin[(wc*2+pt)*16+fr][ks*32+fk];
    #pragma unroll
    for (int lt=0;lt<2;++lt)
      #pragma unroll
      for (int pt=0;pt<2;++pt)
        acc[lt][pt] = __builtin_amdgcn_mfma_f32_16x16x32_f16(a[lt], bb[pt], acc[lt][pt], 0, 0, 0);
  }
  #pragma unroll
  for (int ks = 0; ks < 2; ++ks){
    half8 a[2], bb[2];
    #pragma unroll
    for (int lt=0;lt<2;++lt) a[lt] = *(const half8*)&Ms[(wr*2+lt)*16+fr][ks*32+fk];
    #pragma unroll
    for (int pt=0;pt<2;++pt) bb[pt] = *(const half8*)&xdT[(wc*2+pt)*16+fr][ks*32+fk];
    #pragma unroll
    for (int lt=0;lt<2;++lt)
      #pragma unroll
      for (int pt=0;pt<2;++pt)
        acc[lt][pt] = __builtin_amdgcn_mfma_f32_16x16x32_f16(a[lt], bb[pt], acc[lt][pt], 0, 0, 0);
  }
  float Dh = Dp[h];
  #pragma unroll
  for (int lt=0;lt<2;++lt){
    int l0 = (wr*2+lt)*16 + (ln>>4)*4;
    #pragma unroll
    for (int pt=0;pt<2;++pt){
      int p = (wc*2+pt)*16 + fr;
      #pragma unroll
      for (int j=0;j<4;++j){
        int grow = row0 + l0 + j;
        float x = h2f(xBC[(size_t)grow*CONV_DIM + h*HEADDIM + p]);
        float z = h2f(zx[(size_t)grow*DPROJ + h*HEADDIM + p]);
        y_pre[(size_t)grow*D_INNER + h*HEADDIM + p] = f2h((acc[lt][pt][j] + x*Dh) * siluf(z));
      }
    }
  }
}

// per-row RMS scale: sc[row] = rsqrt(mean(ypre^2) + eps)
__global__ __launch_bounds__(256) void rowsc_kernel(const unsigned short* __restrict__ y,
                                                    float* __restrict__ sc) {
  int row = blockIdx.x;
  int t = threadIdx.x;
  const unsigned short* yr = y + (size_t)row*D_INNER + t*8;
  ushort4 a = *(const ushort4*)yr;
  ushort4 bq = *(const ushort4*)(yr+4);
  float ss = 0.f;
  float v;
  v=h2f(a.x); ss+=v*v; v=h2f(a.y); ss+=v*v; v=h2f(a.z); ss+=v*v; v=h2f(a.w); ss+=v*v;
  v=h2f(bq.x); ss+=v*v; v=h2f(bq.y); ss+=v*v; v=h2f(bq.z); ss+=v*v; v=h2f(bq.w); ss+=v*v;
  #pragma unroll
  for (int off=32; off>0; off>>=1) ss += __shfl_down(ss, off, 64);
  __shared__ float wsum[4];
  int wid = t >> 6, lane = t & 63;
  if (lane == 0) wsum[wid] = ss;
  __syncthreads();
  if (t == 0) sc[row] = rsqrtf((wsum[0]+wsum[1]+wsum[2]+wsum[3])/D_INNER + EPSF);
}

extern "C" void kernel_launch(void* const* d_in, const int* in_sizes, int n_in,
                              void* d_out, int out_size, void* d_ws, size_t ws_size,
                              hipStream_t stream) {
  const float* u       = (const float*)d_in[0];
  const float* W_in    = (const float*)d_in[1];
  const float* conv_w  = (const float*)d_in[2];
  const float* conv_b  = (const float*)d_in[3];
  const float* dt_bias = (const float*)d_in[4];
  const float* A_log   = (const float*)d_in[5];
  const float* Dp      = (const float*)d_in[6];
  const float* norm_w  = (const float*)d_in[7];
  const float* W_out   = (const float*)d_in[8];
  float* out = (float*)d_out;

  char* w = (char*)d_ws;
  unsigned short* zx_h   = (unsigned short*)w;  w += (size_t)BL*DPROJ*2;
  unsigned short* xBC_h  = (unsigned short*)w;  w += (size_t)BL*CONV_DIM*2;
  unsigned short* ypre_h = (unsigned short*)w;  w += (size_t)BL*D_INNER*2;
  unsigned short* u_h    = (unsigned short*)w;  w += (size_t)BL*D_MODEL*2;
  unsigned short* Win_h  = (unsigned short*)w;  w += (size_t)NPAD1*D_MODEL*2;
  unsigned short* Wg_h   = (unsigned short*)w;  w += (size_t)D_MODEL*D_INNER*2;
  unsigned short* states = (unsigned short*)w;  w += (size_t)B_SZ*NCHUNK*NHEADS*HEADDIM*D_STATE*2;
  unsigned short* G      = (unsigned short*)w;  w += (size_t)B_SZ*NCHUNK*CHUNK*CHUNK*2;
  float* dt     = (float*)w;  w += (size_t)BL*NHEADS*4;
  float* A_cum  = (float*)w;  w += (size_t)B_SZ*NHEADS*NCHUNK*CHUNK*4;
  float* sc     = (float*)w;  w += (size_t)BL*4;

  // 0) all converts in one launch (Wg = W_out * norm_w, RMS fold)
  cvt_all<<<(NCVT+255)/256, 256, 0, stream>>>(u, W_in, W_out, norm_w, u_h, Win_h, Wg_h);
  // 1) zxbcdt = u @ W_in.T  (fp16 out; includes dt logit columns)
  gemm_f16_pipe<1><<<dim3(NPAD1/128, BL/128), 256, 0, stream>>>(u_h, Win_h, zx_h, nullptr, DPROJ, D_MODEL);
  // 2) dt + per-chunk cumsum (fused, shfl prefix)
  dtacum_kernel<<<B_SZ*NHEADS*NCHUNK, 64, 0, stream>>>(zx_h, dt_bias, A_log, dt, A_cum);
  // 3) depthwise conv + silu (fp16 in/out)
  conv8_kernel<<<((BL/8)*(CONV_DIM/4)+255)/256, 256, 0, stream>>>(zx_h, conv_w, conv_b, xBC_h);
  // 4) G = C B^T per (b,c), fp16 out
  g_kernel<<<B_SZ*NCHUNK*4, 256, 0, stream>>>(xBC_h, G);
  // 5) per-chunk states (MFMA, fp16 out)
  states_mfma<<<B_SZ*NCHUNK*NHEADS, 256, 0, stream>>>(xBC_h, dt, A_cum, states);
  // 6) inter-chunk scan (prefetch-all + serial recurrence), 8-way split
  scan_kernel<<<B_SZ*NHEADS*8, 256, 0, stream>>>(A_cum, states);
  // 7) Y (MFMA), fp16 out (unnormalized)
  y_mfma<<<B_SZ*NCHUNK*NHEADS, 256, 0, stream>>>(xBC_h, zx_h, dt, A_cum, G, states, Dp, ypre_h);
  // 8) per-row RMS scale
  rowsc_kernel<<<BL, 256, 0, stream>>>(ypre_h, sc);
  // 9) out = diag(sc) * (ypre @ (W_out*norm_w).T)  (fp32 out, scaled epilogue)
  gemm_f16_pipe<0><<<dim3(D_MODEL/128, BL/128), 256, 0, stream>>>(ypre_h, Wg_h, out, sc, D_MODEL, D_INNER);
}

// Round 14
// 193.450 us; speedup vs baseline: 1.1127x; 1.0311x over previous
//
#include <hip/hip_runtime.h>
#include <hip/hip_bf16.h>
#include <math.h>

#define D_MODEL 1024
#define D_INNER 2048
#define D_STATE 128
#define NHEADS 32
#define HEADDIM 64
#define CHUNK 64
#define B_SZ 2
#define LSEQ 2048
#define BL (B_SZ*LSEQ)                              // 4096
#define DPROJ (2*D_INNER + 2*D_STATE + NHEADS)      // 4384
#define CONV_DIM (D_INNER + 2*D_STATE)              // 2304
#define NCHUNK (LSEQ/CHUNK)                         // 32
#define NPAD1 4480                                  // DPROJ padded to x128
#define EPSF 1e-5f

typedef __attribute__((ext_vector_type(8))) _Float16 half8;
typedef __attribute__((ext_vector_type(4))) _Float16 half4;
typedef __attribute__((ext_vector_type(4))) float f32x4;

__device__ __forceinline__ float siluf(float v){ return v / (1.0f + expf(-v)); }
__device__ __forceinline__ float softplusf(float v){ return v > 20.0f ? v : log1pf(expf(v)); }
__device__ __forceinline__ unsigned short f2h(float x){
  union { _Float16 h; unsigned short u; } v; v.h = (_Float16)x;
  return v.u;
}
__device__ __forceinline__ float h2f(unsigned short x){
  union { unsigned short u; _Float16 h; } v; v.u = x;
  return (float)v.h;
}
__device__ __forceinline__ _Float16 h2h(unsigned short x){
  union { unsigned short u; _Float16 h; } v; v.u = x;
  return v.h;
}

typedef const __attribute__((address_space(1))) void gvoid_t;
typedef __attribute__((address_space(3))) void lvoid_t;
__device__ __forceinline__ void gl_lds16(const void* gsrc, void* ldst) {
  gvoid_t* g = reinterpret_cast<gvoid_t*>((uintptr_t)gsrc);
  lvoid_t* l = reinterpret_cast<lvoid_t*>((unsigned int)(uintptr_t)ldst);
  __builtin_amdgcn_global_load_lds(g, l, 16, 0, 0);
}

#define NU4  (BL*D_MODEL/4)
#define NW4  (NPAD1*D_MODEL/4)
#define NWo4 (D_MODEL*D_INNER/4)
#define NCVT (NU4+NW4+NWo4)

// ---------- fused converters ----------
__global__ void cvt_all(const float* __restrict__ u, const float* __restrict__ W_in,
                        const float* __restrict__ W_out, const float* __restrict__ norm_w,
                        unsigned short* __restrict__ u_h, unsigned short* __restrict__ Win_h,
                        unsigned short* __restrict__ Wg_h) {
  int i = blockIdx.x*256 + threadIdx.x;
  if (i >= NCVT) return;
  if (i < NU4) {
    float4 v = *(const float4*)(u + (size_t)i*4);
    ushort4 o; o.x=f2h(v.x); o.y=f2h(v.y); o.z=f2h(v.z); o.w=f2h(v.w);
    *(ushort4*)(u_h + (size_t)i*4) = o;
  } else if (i < NU4 + NW4) {
    int q = i - NU4;
    int row = q / (D_MODEL/4);
    ushort4 o; o.x=0; o.y=0; o.z=0; o.w=0;
    if (row < DPROJ) {
      float4 v = *(const float4*)(W_in + (size_t)q*4);
      o.x=f2h(v.x); o.y=f2h(v.y); o.z=f2h(v.z); o.w=f2h(v.w);
    }
    *(ushort4*)(Win_h + (size_t)q*4) = o;
  } else {
    int q = i - NU4 - NW4;
    int colq = q % (D_INNER/4);
    float4 v = *(const float4*)(W_out + (size_t)q*4);
    float4 g = *(const float4*)(norm_w + (size_t)colq*4);
    ushort4 o; o.x=f2h(v.x*g.x); o.y=f2h(v.y*g.y); o.z=f2h(v.z*g.z); o.w=f2h(v.w*g.w);
    *(ushort4*)(Wg_h + (size_t)q*4) = o;
  }
}

// ---------- pipelined fp16 MFMA GEMM; 4 slots, 2 K-tiles per barrier pair ----------
template<int OUT_F16>
__global__ __launch_bounds__(256) void gemm_f16_pipe(const unsigned short* __restrict__ A,
    const unsigned short* __restrict__ W, void* __restrict__ Cv,
    const float* __restrict__ Sc, int N, int K) {
  __shared__ unsigned short lds[4*2*4096];          // 64 KB -> 2 blocks/CU
  const int t   = threadIdx.x;
  const int wid = t >> 6, l = t & 63;
  const int nwg = gridDim.x * gridDim.y;
  int bid = blockIdx.y * gridDim.x + blockIdx.x;
  int swz = (bid & 7) * (nwg >> 3) + (bid >> 3);    // XCD-chunked (nwg%8==0)
  const int m0 = (swz / gridDim.x) * 128;
  const int n0 = (swz % gridDim.x) * 128;
  const int wr = wid >> 1, wc = wid & 1;
  const int fr = l & 15, cg = l >> 4;
  const int NT = K >> 5;                            // NT even (K=1024/2048)

  int srow[2]; int scol[2];
  #pragma unroll
  for (int i=0;i<2;++i){
    int s = i*256 + t;
    int r = s >> 2, c = s & 3;
    int sw = (r + (r>>2)) & 3;
    srow[i] = r; scol[i] = (c ^ sw) * 8;
  }
  const unsigned short* Abase = A + (size_t)m0 * K;
  const unsigned short* Wbase = W + (size_t)n0 * K;

#define STAGE(tt, slot) { \
    int kk = (tt) << 5; \
    unsigned short* La = &lds[(slot)*8192]; \
    unsigned short* Lb = &lds[(slot)*8192 + 4096]; \
    gl_lds16(Abase + (size_t)srow[0]*K + kk + scol[0], (char*)La + (0*256+t)*16); \
    gl_lds16(Abase + (size_t)srow[1]*K + kk + scol[1], (char*)La + (1*256+t)*16); \
    gl_lds16(Wbase + (size_t)srow[0]*K + kk + scol[0], (char*)Lb + (0*256+t)*16); \
    gl_lds16(Wbase + (size_t)srow[1]*K + kk + scol[1], (char*)Lb + (1*256+t)*16); \
  }

#define COMPUTE(slot) { \
    const unsigned short* La = &lds[(slot)*8192]; \
    const unsigned short* Lb = &lds[(slot)*8192 + 4096]; \
    half8 af[4], bfv[4]; \
    _Pragma("unroll") \
    for (int m=0;m<4;++m){ \
      int r = wr*64 + m*16 + fr; \
      int sw = (r + (r>>2)) & 3; \
      af[m] = *(const half8*)&La[(r*4 + (cg ^ sw))*8]; \
    } \
    _Pragma("unroll") \
    for (int n=0;n<4;++n){ \
      int r = wc*64 + n*16 + fr; \
      int sw = (r + (r>>2)) & 3; \
      bfv[n] = *(const half8*)&Lb[(r*4 + (cg ^ sw))*8]; \
    } \
    __builtin_amdgcn_s_setprio(1); \
    _Pragma("unroll") \
    for (int m=0;m<4;++m) \
      _Pragma("unroll") \
      for (int n=0;n<4;++n) \
        acc[m][n] = __builtin_amdgcn_mfma_f32_16x16x32_f16(af[m], bfv[n], acc[m][n], 0, 0, 0); \
    __builtin_amdgcn_s_setprio(0); \
  }

  f32x4 acc[4][4] = {};
  STAGE(0, 0);
  STAGE(1, 1);
  STAGE(2, 2);
  STAGE(3, 3);

  for (int tt = 0; tt < NT; tt += 2) {
    // tiles tt, tt+1 must be resident; tiles tt+2, tt+3 may remain in flight
    if (tt + 4 < NT) { asm volatile("s_waitcnt vmcnt(8)" ::: "memory"); }
    else             { asm volatile("s_waitcnt vmcnt(0)" ::: "memory"); }
    __builtin_amdgcn_s_barrier();
    asm volatile("" ::: "memory");

    COMPUTE(tt & 3);
    COMPUTE((tt + 1) & 3);

    asm volatile("s_waitcnt lgkmcnt(0)" ::: "memory");
    __builtin_amdgcn_s_barrier();                   // all reads of slots tt,tt+1 done
    asm volatile("" ::: "memory");
    if (tt + 4 < NT) {
      STAGE(tt + 4, (tt + 4) & 3);
      if (tt + 5 < NT) STAGE(tt + 5, (tt + 5) & 3);
    }
  }
#undef COMPUTE
#undef STAGE

  const int crow = m0 + wr*64 + (l >> 4) * 4;
  const int ccol0 = n0 + wc*64 + fr;
  #pragma unroll
  for (int m = 0; m < 4; ++m) {
    #pragma unroll
    for (int n = 0; n < 4; ++n) {
      int col = ccol0 + n*16;
      if (col < N) {
        if (OUT_F16) {
          unsigned short* cp = (unsigned short*)Cv + (size_t)(crow + m*16)*N + col;
          #pragma unroll
          for (int j = 0; j < 4; ++j) cp[(size_t)j*N] = f2h(acc[m][n][j]);
        } else {
          float* cp = (float*)Cv + (size_t)(crow + m*16)*N + col;
          #pragma unroll
          for (int j = 0; j < 4; ++j) cp[(size_t)j*N] = acc[m][n][j] * Sc[crow + m*16 + j];
        }
      }
    }
  }
}

// ---------- fused dt + per-chunk cumsum ----------
__global__ __launch_bounds__(64) void dtacum_kernel(const unsigned short* __restrict__ zx,
    const float* __restrict__ dt_bias, const float* __restrict__ A_log,
    float* __restrict__ dt, float* __restrict__ A_cum) {
  int blk = blockIdx.x;                             // (b*32+h)*32+c
  int c = blk & 31, h = (blk >> 5) & 31, b = blk >> 10;
  int l = threadIdx.x;
  int row = b*LSEQ + c*CHUNK + l;
  float v = h2f(zx[(size_t)row*DPROJ + (2*D_INNER + 2*D_STATE) + h]) + dt_bias[h];
  float dtv = softplusf(v);
  dt[row*NHEADS + h] = dtv;
  float val = -expf(A_log[h]) * dtv;
  #pragma unroll
  for (int off = 1; off < 64; off <<= 1) {
    float nv = __shfl_up(val, off, 64);
    if (l >= off) val += nv;
  }
  A_cum[blk*64 + l] = val;
}

// causal depthwise conv (K=4) + bias + silu; fp16 in/out; 8 rows x 4 channels per thread
__global__ __launch_bounds__(256) void conv8_kernel(const unsigned short* __restrict__ zx,
    const float* __restrict__ w, const float* __restrict__ bias, unsigned short* __restrict__ xBC) {
  int idx = blockIdx.x*256 + threadIdx.x;           // over (BL/8) * (CONV_DIM/4)
  if (idx >= (BL/8)*(CONV_DIM/4)) return;
  int c4  = idx % (CONV_DIM/4);
  int rb  = idx / (CONV_DIM/4);
  int ch  = c4 * 4;
  int row0 = rb * 8;
  int l0   = row0 & (LSEQ-1);
  float4 r[11];
  #pragma unroll
  for (int jj=0;jj<11;++jj){
    int li = l0 + jj - 3;
    if (li >= 0) {
      ushort4 v = *(const ushort4*)&zx[(size_t)(row0 + jj - 3)*DPROJ + D_INNER + ch];
      r[jj] = make_float4(h2f(v.x), h2f(v.y), h2f(v.z), h2f(v.w));
    } else r[jj] = make_float4(0.f,0.f,0.f,0.f);
  }
  float4 wv[4];
  #pragma unroll
  for (int c=0;c<4;++c) wv[c] = *(const float4*)&w[(ch+c)*4];
  float4 bv = *(const float4*)&bias[ch];
  #pragma unroll
  for (int j=0;j<8;++j){
    float4 acc = bv;
    acc.x += wv[0].x*r[j].x + wv[0].y*r[j+1].x + wv[0].z*r[j+2].x + wv[0].w*r[j+3].x;
    acc.y += wv[1].x*r[j].y + wv[1].y*r[j+1].y + wv[1].z*r[j+2].y + wv[1].w*r[j+3].y;
    acc.z += wv[2].x*r[j].z + wv[2].y*r[j+1].z + wv[2].z*r[j+2].z + wv[2].w*r[j+3].z;
    acc.w += wv[3].x*r[j].w + wv[3].y*r[j+1].w + wv[3].z*r[j+2].w + wv[3].w*r[j+3].w;
    ushort4 o; o.x=f2h(siluf(acc.x)); o.y=f2h(siluf(acc.y)); o.z=f2h(siluf(acc.z)); o.w=f2h(siluf(acc.w));
    *(ushort4*)&xBC[(size_t)(row0+j)*CONV_DIM + ch] = o;
  }
}

// G[b,c][l][s] = sum_n C[l,n] * B[s,n]; 4 blocks per (b,c); fp16 G out
__global__ __launch_bounds__(256) void g_kernel(const unsigned short* __restrict__ xBC,
                                                unsigned short* __restrict__ G) {
  int blk = blockIdx.x >> 2;                        // b*32 + c
  int lq  = blockIdx.x & 3;
  int b = blk >> 5, c = blk & 31;
  __shared__ float Bsh[64][129];
  int t = threadIdx.x;
  int row0 = b*LSEQ + c*CHUNK;
  #pragma unroll
  for (int j=0;j<8;++j){
    int e0 = (j*256 + t)*4;                         // 0..8191
    int s = e0 >> 7, n = e0 & 127;
    ushort4 v = *(const ushort4*)&xBC[(size_t)(row0+s)*CONV_DIM + D_INNER + n];
    Bsh[s][n+0] = h2f(v.x); Bsh[s][n+1] = h2f(v.y);
    Bsh[s][n+2] = h2f(v.z); Bsh[s][n+3] = h2f(v.w);
  }
  __syncthreads();
  int l = lq*16 + (t >> 4), s0 = (t & 15) * 4;
  const unsigned short* Cp = &xBC[(size_t)(row0+l)*CONV_DIM + D_INNER + D_STATE];
  float acc[4] = {};
  #pragma unroll 4
  for (int n4=0;n4<32;++n4){
    ushort4 cv4 = *(const ushort4*)&Cp[n4*4];
    float cv[4] = { h2f(cv4.x), h2f(cv4.y), h2f(cv4.z), h2f(cv4.w) };
    #pragma unroll
    for (int k=0;k<4;++k){
      #pragma unroll
      for (int j=0;j<4;++j) acc[j] += cv[k] * Bsh[s0+j][n4*4+k];
    }
  }
  unsigned short* Gp = &G[(size_t)blk*4096 + l*64 + s0];
  ushort4 o; o.x=f2h(acc[0]); o.y=f2h(acc[1]); o.z=f2h(acc[2]); o.w=f2h(acc[3]);
  *(ushort4*)Gp = o;
}

// ---------- MFMA states (fp16 out, vectorized staging) ----------
__global__ __launch_bounds__(256) void states_mfma(const unsigned short* __restrict__ xBC,
    const float* __restrict__ dt, const float* __restrict__ A_cum, unsigned short* __restrict__ states) {
  int blk = blockIdx.x;                             // (b*32+c)*32+h
  int h = blk & 31, c = (blk>>5)&31, b = blk>>10;
  __shared__ _Float16 Bt[128][72];                  // [n][s]
  __shared__ _Float16 xdT[64][72];                  // [p][s]
  __shared__ float Ac[64], dtl[64];
  int t = threadIdx.x;
  int wid = t >> 6, ln = t & 63;
  int row0 = b*LSEQ + c*CHUNK;
  if (t < 64){ Ac[t] = A_cum[((b*32+h)*32 + c)*64 + t]; dtl[t] = dt[(row0+t)*NHEADS + h]; }
  __syncthreads();
  float AcL = Ac[63];
  #pragma unroll
  for (int j=0;j<8;++j){
    int e0 = (j*256+t)*4;                           // 0..8191
    int s = e0 >> 7, n = e0 & 127;
    ushort4 v = *(const ushort4*)&xBC[(size_t)(row0+s)*CONV_DIM + D_INNER + n];
    Bt[n+0][s] = h2h(v.x); Bt[n+1][s] = h2h(v.y);
    Bt[n+2][s] = h2h(v.z); Bt[n+3][s] = h2h(v.w);
  }
  #pragma unroll
  for (int j=0;j<4;++j){
    int e0 = (j*256+t)*4;                           // 0..4095
    int s = e0 >> 6, p = e0 & 63;
    float sc = dtl[s] * expf(AcL - Ac[s]);
    ushort4 v = *(const ushort4*)&xBC[(size_t)(row0+s)*CONV_DIM + h*HEADDIM + p];
    xdT[p+0][s] = (_Float16)(h2f(v.x)*sc);
    xdT[p+1][s] = (_Float16)(h2f(v.y)*sc);
    xdT[p+2][s] = (_Float16)(h2f(v.z)*sc);
    xdT[p+3][s] = (_Float16)(h2f(v.w)*sc);
  }
  __syncthreads();
  const int fr = ln & 15, fk = (ln >> 4) * 8;
  f32x4 acc[4][2] = {};
  #pragma unroll
  for (int ks = 0; ks < 2; ++ks){
    half8 a[4], bb[2];
    #pragma unroll
    for (int pt=0;pt<4;++pt) a[pt] = *(const half8*)&xdT[pt*16+fr][ks*32+fk];
    #pragma unroll
    for (int nt=0;nt<2;++nt) bb[nt] = *(const half8*)&Bt[(wid*2+nt)*16+fr][ks*32+fk];
    #pragma unroll
    for (int pt=0;pt<4;++pt)
      #pragma unroll
      for (int nt=0;nt<2;++nt)
        acc[pt][nt] = __builtin_amdgcn_mfma_f32_16x16x32_f16(a[pt], bb[nt], acc[pt][nt], 0, 0, 0);
  }
  unsigned short* Sp = &states[(size_t)blk*8192];
  #pragma unroll
  for (int pt=0;pt<4;++pt){
    int p0 = pt*16 + (ln>>4)*4;
    #pragma unroll
    for (int nt=0;nt<2;++nt){
      int n = (wid*2+nt)*16 + fr;
      #pragma unroll
      for (int j=0;j<4;++j) Sp[(p0+j)*128 + n] = f2h(acc[pt][nt][j]);
    }
  }
}

// inter-chunk scan: prefetch all chunk values, then serial VALU recurrence + stores
__global__ __launch_bounds__(256) void scan_kernel(const float* __restrict__ A_cum,
                                                   unsigned short* __restrict__ states) {
  int g  = blockIdx.x & 7;
  int bh = blockIdx.x >> 3;
  int b = bh >> 5, h = bh & 31;
  int t = threadIdx.x;
  int off = g*1024 + t*4;
  ushort4 tmp[NCHUNK];
  float dec[NCHUNK];
  #pragma unroll
  for (int c=0;c<NCHUNK;++c){
    tmp[c] = *(const ushort4*)&states[(size_t)((b*32+c)*32 + h)*8192 + off];
    dec[c] = A_cum[((b*32+h)*32 + c)*64 + 63];
  }
  float s0=0.f, s1=0.f, s2=0.f, s3=0.f;
  #pragma unroll
  for (int c=0;c<NCHUNK;++c){
    float d = expf(dec[c]);
    ushort4 o; o.x=f2h(s0); o.y=f2h(s1); o.z=f2h(s2); o.w=f2h(s3);
    *(ushort4*)&states[(size_t)((b*32+c)*32 + h)*8192 + off] = o;
    s0 = s0*d + h2f(tmp[c].x);
    s1 = s1*d + h2f(tmp[c].y);
    s2 = s2*d + h2f(tmp[c].z);
    s3 = s3*d + h2f(tmp[c].w);
  }
}

// ---------- MFMA Y (vectorized staging, fp16 G) ----------
__global__ __launch_bounds__(256) void y_mfma(const unsigned short* __restrict__ xBC,
    const unsigned short* __restrict__ zx, const float* __restrict__ dt,
    const float* __restrict__ A_cum, const unsigned short* __restrict__ G,
    const unsigned short* __restrict__ states, const float* __restrict__ Dp,
    unsigned short* __restrict__ y_pre) {
  int blk = blockIdx.x;                             // (b*32+c)*32+h
  int h = blk & 31, c = (blk>>5)&31, b = blk>>10;
  __shared__ _Float16 Cl[64][136];
  __shared__ _Float16 Sin[64][136];
  __shared__ _Float16 Ms[64][72];
  __shared__ _Float16 xdT[64][72];
  __shared__ float Ac[64], dtl[64];
  int t = threadIdx.x;
  int wid = t >> 6, ln = t & 63;
  int row0 = b*LSEQ + c*CHUNK;
  if (t < 64){ Ac[t] = A_cum[((b*32+h)*32 + c)*64 + t]; dtl[t] = dt[(row0+t)*NHEADS + h]; }
  __syncthreads();
  #pragma unroll
  for (int j=0;j<8;++j){
    int e0 = (j*256+t)*4; int l = e0>>7, n = e0&127;
    float sc = expf(Ac[l]);
    ushort4 v = *(const ushort4*)&xBC[(size_t)(row0+l)*CONV_DIM + D_INNER + D_STATE + n];
    half4 hv = { (_Float16)(h2f(v.x)*sc), (_Float16)(h2f(v.y)*sc),
                 (_Float16)(h2f(v.z)*sc), (_Float16)(h2f(v.w)*sc) };
    *(half4*)&Cl[l][n] = hv;
  }
  {
    const unsigned short* Sg = &states[(size_t)blk*8192];
    #pragma unroll
    for (int j=0;j<8;++j){
      int elem = (j*256+t)*4; int p = elem>>7, n = elem&127;
      ushort4 v = *(const ushort4*)&Sg[elem];
      half4 hv = { h2h(v.x), h2h(v.y), h2h(v.z), h2h(v.w) };
      *(half4*)&Sin[p][n] = hv;
    }
  }
  #pragma unroll
  for (int j=0;j<4;++j){
    int e0 = (j*256+t)*4; int s = e0>>6, p = e0&63;
    float sc = dtl[s];
    ushort4 v = *(const ushort4*)&xBC[(size_t)(row0+s)*CONV_DIM + h*HEADDIM + p];
    xdT[p+0][s] = (_Float16)(h2f(v.x)*sc);
    xdT[p+1][s] = (_Float16)(h2f(v.y)*sc);
    xdT[p+2][s] = (_Float16)(h2f(v.z)*sc);
    xdT[p+3][s] = (_Float16)(h2f(v.w)*sc);
  }
  {
    const unsigned short* Gp = &G[(size_t)(b*32+c)*4096];
    #pragma unroll
    for (int j=0;j<4;++j){
      int e0 = (j*256+t)*4; int l = e0>>6, s = e0&63;
      ushort4 gv = *(const ushort4*)&Gp[e0];
      float al = Ac[l];
      Ms[l][s+0] = (s+0 <= l) ? (_Float16)(h2f(gv.x) * expf(al-Ac[s+0])) : (_Float16)0.f;
      Ms[l][s+1] = (s+1 <= l) ? (_Float16)(h2f(gv.y) * expf(al-Ac[s+1])) : (_Float16)0.f;
      Ms[l][s+2] = (s+2 <= l) ? (_Float16)(h2f(gv.z) * expf(al-Ac[s+2])) : (_Float16)0.f;
      Ms[l][s+3] = (s+3 <= l) ? (_Float16)(h2f(gv.w) * expf(al-Ac[s+3])) : (_Float16)0.f;
    }
  }
  __syncthreads();
  const int wr = wid >> 1, wc = wid & 1;
  const int fr = ln & 15, fk = (ln >> 4) * 8;
  f32x4 acc[2][2] = {};
  #pragma unroll
  for (int ks = 0; ks < 4; ++ks){
    half8 a[2], bb[2];
    #pragma unroll
    for (int lt=0;lt<2;++lt) a[lt] = *(const half8*)&Cl[(wr*2+lt)*16+fr][ks*32+fk];
    #pragma unroll
    for (int pt=0;pt<2;++pt) bb[pt] = *(const half8*)&Sin[(wc*2+pt)*16+fr][ks*32+fk];
    #pragma unroll
    for (int lt=0;lt<2;++lt)
      #pragma unroll
      for (int pt=0;pt<2;++pt)
        acc[lt][pt] = __builtin_amdgcn_mfma_f32_16x16x32_f16(a[lt], bb[pt], acc[lt][pt], 0, 0, 0);
  }
  #pragma unroll
  for (int ks = 0; ks < 2; ++ks){
    half8 a[2], bb[2];
    #pragma unroll
    for (int lt=0;lt<2;++lt) a[lt] = *(const half8*)&Ms[(wr*2+lt)*16+fr][ks*32+fk];
    #pragma unroll
    for (int pt=0;pt<2;++pt) bb[pt] = *(const half8*)&xdT[(wc*2+pt)*16+fr][ks*32+fk];
    #pragma unroll
    for (int lt=0;lt<2;++lt)
      #pragma unroll
      for (int pt=0;pt<2;++pt)
        acc[lt][pt] = __builtin_amdgcn_mfma_f32_16x16x32_f16(a[lt], bb[pt], acc[lt][pt], 0, 0, 0);
  }
  float Dh = Dp[h];
  #pragma unroll
  for (int lt=0;lt<2;++lt){
    int l0 = (wr*2+lt)*16 + (ln>>4)*4;
    #pragma unroll
    for (int pt=0;pt<2;++pt){
      int p = (wc*2+pt)*16 + fr;
      #pragma unroll
      for (int j=0;j<4;++j){
        int grow = row0 + l0 + j;
        float x = h2f(xBC[(size_t)grow*CONV_DIM + h*HEADDIM + p]);
        float z = h2f(zx[(size_t)grow*DPROJ + h*HEADDIM + p]);
        y_pre[(size_t)grow*D_INNER + h*HEADDIM + p] = f2h((acc[lt][pt][j] + x*Dh) * siluf(z));
      }
    }
  }
}

// per-row RMS scale: sc[row] = rsqrt(mean(ypre^2) + eps)
__global__ __launch_bounds__(256) void rowsc_kernel(const unsigned short* __restrict__ y,
                                                    float* __restrict__ sc) {
  int row = blockIdx.x;
  int t = threadIdx.x;
  const unsigned short* yr = y + (size_t)row*D_INNER + t*8;
  ushort4 a = *(const ushort4*)yr;
  ushort4 bq = *(const ushort4*)(yr+4);
  float ss = 0.f;
  float v;
  v=h2f(a.x); ss+=v*v; v=h2f(a.y); ss+=v*v; v=h2f(a.z); ss+=v*v; v=h2f(a.w); ss+=v*v;
  v=h2f(bq.x); ss+=v*v; v=h2f(bq.y); ss+=v*v; v=h2f(bq.z); ss+=v*v; v=h2f(bq.w); ss+=v*v;
  #pragma unroll
  for (int off=32; off>0; off>>=1) ss += __shfl_down(ss, off, 64);
  __shared__ float wsum[4];
  int wid = t >> 6, lane = t & 63;
  if (lane == 0) wsum[wid] = ss;
  __syncthreads();
  if (t == 0) sc[row] = rsqrtf((wsum[0]+wsum[1]+wsum[2]+wsum[3])/D_INNER + EPSF);
}

extern "C" void kernel_launch(void* const* d_in, const int* in_sizes, int n_in,
                              void* d_out, int out_size, void* d_ws, size_t ws_size,
                              hipStream_t stream) {
  const float* u       = (const float*)d_in[0];
  const float* W_in    = (const float*)d_in[1];
  const float* conv_w  = (const float*)d_in[2];
  const float* conv_b  = (const float*)d_in[3];
  const float* dt_bias = (const float*)d_in[4];
  const float* A_log   = (const float*)d_in[5];
  const float* Dp      = (const float*)d_in[6];
  const float* norm_w  = (const float*)d_in[7];
  const float* W_out   = (const float*)d_in[8];
  float* out = (float*)d_out;

  char* w = (char*)d_ws;
  unsigned short* zx_h   = (unsigned short*)w;  w += (size_t)BL*DPROJ*2;
  unsigned short* xBC_h  = (unsigned short*)w;  w += (size_t)BL*CONV_DIM*2;
  unsigned short* ypre_h = (unsigned short*)w;  w += (size_t)BL*D_INNER*2;
  unsigned short* u_h    = (unsigned short*)w;  w += (size_t)BL*D_MODEL*2;
  unsigned short* Win_h  = (unsigned short*)w;  w += (size_t)NPAD1*D_MODEL*2;
  unsigned short* Wg_h   = (unsigned short*)w;  w += (size_t)D_MODEL*D_INNER*2;
  unsigned short* states = (unsigned short*)w;  w += (size_t)B_SZ*NCHUNK*NHEADS*HEADDIM*D_STATE*2;
  unsigned short* G      = (unsigned short*)w;  w += (size_t)B_SZ*NCHUNK*CHUNK*CHUNK*2;
  float* dt     = (float*)w;  w += (size_t)BL*NHEADS*4;
  float* A_cum  = (float*)w;  w += (size_t)B_SZ*NHEADS*NCHUNK*CHUNK*4;
  float* sc     = (float*)w;  w += (size_t)BL*4;

  // 0) all converts in one launch (Wg = W_out * norm_w, RMS fold)
  cvt_all<<<(NCVT+255)/256, 256, 0, stream>>>(u, W_in, W_out, norm_w, u_h, Win_h, Wg_h);
  // 1) zxbcdt = u @ W_in.T  (fp16 out; includes dt logit columns)
  gemm_f16_pipe<1><<<dim3(NPAD1/128, BL/128), 256, 0, stream>>>(u_h, Win_h, zx_h, nullptr, DPROJ, D_MODEL);
  // 2) dt + per-chunk cumsum (fused, shfl prefix)
  dtacum_kernel<<<B_SZ*NHEADS*NCHUNK, 64, 0, stream>>>(zx_h, dt_bias, A_log, dt, A_cum);
  // 3) depthwise conv + silu (fp16 in/out)
  conv8_kernel<<<((BL/8)*(CONV_DIM/4)+255)/256, 256, 0, stream>>>(zx_h, conv_w, conv_b, xBC_h);
  // 4) G = C B^T per (b,c), fp16 out
  g_kernel<<<B_SZ*NCHUNK*4, 256, 0, stream>>>(xBC_h, G);
  // 5) per-chunk states (MFMA, fp16 out)
  states_mfma<<<B_SZ*NCHUNK*NHEADS, 256, 0, stream>>>(xBC_h, dt, A_cum, states);
  // 6) inter-chunk scan (prefetch-all + serial recurrence), 8-way split
  scan_kernel<<<B_SZ*NHEADS*8, 256, 0, stream>>>(A_cum, states);
  // 7) Y (MFMA), fp16 out (unnormalized)
  y_mfma<<<B_SZ*NCHUNK*NHEADS, 256, 0, stream>>>(xBC_h, zx_h, dt, A_cum, G, states, Dp, ypre_h);
  // 8) per-row RMS scale
  rowsc_kernel<<<BL, 256, 0, stream>>>(ypre_h, sc);
  // 9) out = diag(sc) * (ypre @ (W_out*norm_w).T)  (fp32 out, scaled epilogue)
  gemm_f16_pipe<0><<<dim3(D_MODEL/128, BL/128), 256, 0, stream>>>(ypre_h, Wg_h, out, sc, D_MODEL, D_INNER);
}

// Round 15
// 187.497 us; speedup vs baseline: 1.1481x; 1.0318x over previous
//
#include <hip/hip_runtime.h>
#include <hip/hip_bf16.h>
#include <math.h>

#define D_MODEL 1024
#define D_INNER 2048
#define D_STATE 128
#define NHEADS 32
#define HEADDIM 64
#define CHUNK 64
#define B_SZ 2
#define LSEQ 2048
#define BL (B_SZ*LSEQ)                              // 4096
#define DPROJ (2*D_INNER + 2*D_STATE + NHEADS)      // 4384
#define CONV_DIM (D_INNER + 2*D_STATE)              // 2304
#define NCHUNK (LSEQ/CHUNK)                         // 32
#define NPAD1 4480                                  // DPROJ padded to x128
#define EPSF 1e-5f

typedef __attribute__((ext_vector_type(8))) _Float16 half8;
typedef __attribute__((ext_vector_type(4))) _Float16 half4;
typedef __attribute__((ext_vector_type(4))) float f32x4;

__device__ __forceinline__ float siluf(float v){ return v / (1.0f + expf(-v)); }
__device__ __forceinline__ float softplusf(float v){ return v > 20.0f ? v : log1pf(expf(v)); }
__device__ __forceinline__ unsigned short f2h(float x){
  union { _Float16 h; unsigned short u; } v; v.h = (_Float16)x;
  return v.u;
}
__device__ __forceinline__ float h2f(unsigned short x){
  union { unsigned short u; _Float16 h; } v; v.u = x;
  return (float)v.h;
}
__device__ __forceinline__ _Float16 h2h(unsigned short x){
  union { unsigned short u; _Float16 h; } v; v.u = x;
  return v.h;
}

typedef const __attribute__((address_space(1))) void gvoid_t;
typedef __attribute__((address_space(3))) void lvoid_t;
__device__ __forceinline__ void gl_lds16(const void* gsrc, void* ldst) {
  gvoid_t* g = reinterpret_cast<gvoid_t*>((uintptr_t)gsrc);
  lvoid_t* l = reinterpret_cast<lvoid_t*>((unsigned int)(uintptr_t)ldst);
  __builtin_amdgcn_global_load_lds(g, l, 16, 0, 0);
}

#define NU4  (BL*D_MODEL/4)
#define NW4  (NPAD1*D_MODEL/4)
#define NWo4 (D_MODEL*D_INNER/4)
#define NCVT (NU4+NW4+NWo4)

// ---------- fused converters ----------
__global__ void cvt_all(const float* __restrict__ u, const float* __restrict__ W_in,
                        const float* __restrict__ W_out, const float* __restrict__ norm_w,
                        unsigned short* __restrict__ u_h, unsigned short* __restrict__ Win_h,
                        unsigned short* __restrict__ Wg_h) {
  int i = blockIdx.x*256 + threadIdx.x;
  if (i >= NCVT) return;
  if (i < NU4) {
    float4 v = *(const float4*)(u + (size_t)i*4);
    ushort4 o; o.x=f2h(v.x); o.y=f2h(v.y); o.z=f2h(v.z); o.w=f2h(v.w);
    *(ushort4*)(u_h + (size_t)i*4) = o;
  } else if (i < NU4 + NW4) {
    int q = i - NU4;
    int row = q / (D_MODEL/4);
    ushort4 o; o.x=0; o.y=0; o.z=0; o.w=0;
    if (row < DPROJ) {
      float4 v = *(const float4*)(W_in + (size_t)q*4);
      o.x=f2h(v.x); o.y=f2h(v.y); o.z=f2h(v.z); o.w=f2h(v.w);
    }
    *(ushort4*)(Win_h + (size_t)q*4) = o;
  } else {
    int q = i - NU4 - NW4;
    int colq = q % (D_INNER/4);
    float4 v = *(const float4*)(W_out + (size_t)q*4);
    float4 g = *(const float4*)(norm_w + (size_t)colq*4);
    ushort4 o; o.x=f2h(v.x*g.x); o.y=f2h(v.y*g.y); o.z=f2h(v.z*g.z); o.w=f2h(v.w*g.w);
    *(ushort4*)(Wg_h + (size_t)q*4) = o;
  }
}

// ---------- pipelined fp16 MFMA GEMM; 4 slots, 2 K-tiles per barrier pair ----------
// XCD-region block mapping: XCD k owns a (gy/8)-row-band x all-cols region,
// swept column-major with per-XCD column stagger -> A-set resident in per-XCD L2.
template<int OUT_F16>
__global__ __launch_bounds__(256) void gemm_f16_pipe(const unsigned short* __restrict__ A,
    const unsigned short* __restrict__ W, void* __restrict__ Cv,
    const float* __restrict__ Sc, int N, int K) {
  __shared__ unsigned short lds[4*2*4096];          // 64 KB -> 2 blocks/CU
  const int t   = threadIdx.x;
  const int wid = t >> 6, l = t & 63;
  const int gx = gridDim.x, gy = gridDim.y;         // gy % 8 == 0
  int bid = blockIdx.y * gx + blockIdx.x;
  int k   = bid & 7;                                // XCD (hw round-robin)
  int j   = bid >> 3;                               // index within XCD
  int rpx = gy >> 3;                                // row-bands per XCD
  int r   = j % rpx;
  int colIdx = j / rpx;
  int row = k*rpx + r;
  int col = colIdx + k*(gx >> 3); if (col >= gx) col -= gx * ((col)/gx);
  col = (colIdx + k*(gx >> 3)) % gx;
  const int m0 = row * 128;
  const int n0 = col * 128;
  const int wr = wid >> 1, wc = wid & 1;
  const int fr = l & 15, cg = l >> 4;
  const int NT = K >> 5;                            // NT even (K=1024/2048)

  int srow[2]; int scol[2];
  #pragma unroll
  for (int i=0;i<2;++i){
    int s = i*256 + t;
    int rr = s >> 2, c = s & 3;
    int sw = (rr + (rr>>2)) & 3;
    srow[i] = rr; scol[i] = (c ^ sw) * 8;
  }
  const unsigned short* Abase = A + (size_t)m0 * K;
  const unsigned short* Wbase = W + (size_t)n0 * K;

#define STAGE(tt, slot) { \
    int kk = (tt) << 5; \
    unsigned short* La = &lds[(slot)*8192]; \
    unsigned short* Lb = &lds[(slot)*8192 + 4096]; \
    gl_lds16(Abase + (size_t)srow[0]*K + kk + scol[0], (char*)La + (0*256+t)*16); \
    gl_lds16(Abase + (size_t)srow[1]*K + kk + scol[1], (char*)La + (1*256+t)*16); \
    gl_lds16(Wbase + (size_t)srow[0]*K + kk + scol[0], (char*)Lb + (0*256+t)*16); \
    gl_lds16(Wbase + (size_t)srow[1]*K + kk + scol[1], (char*)Lb + (1*256+t)*16); \
  }

#define COMPUTE(slot) { \
    const unsigned short* La = &lds[(slot)*8192]; \
    const unsigned short* Lb = &lds[(slot)*8192 + 4096]; \
    half8 af[4], bfv[4]; \
    _Pragma("unroll") \
    for (int m=0;m<4;++m){ \
      int rr = wr*64 + m*16 + fr; \
      int sw = (rr + (rr>>2)) & 3; \
      af[m] = *(const half8*)&La[(rr*4 + (cg ^ sw))*8]; \
    } \
    _Pragma("unroll") \
    for (int n=0;n<4;++n){ \
      int rr = wc*64 + n*16 + fr; \
      int sw = (rr + (rr>>2)) & 3; \
      bfv[n] = *(const half8*)&Lb[(rr*4 + (cg ^ sw))*8]; \
    } \
    __builtin_amdgcn_s_setprio(1); \
    _Pragma("unroll") \
    for (int m=0;m<4;++m) \
      _Pragma("unroll") \
      for (int n=0;n<4;++n) \
        acc[m][n] = __builtin_amdgcn_mfma_f32_16x16x32_f16(af[m], bfv[n], acc[m][n], 0, 0, 0); \
    __builtin_amdgcn_s_setprio(0); \
  }

  f32x4 acc[4][4] = {};
  STAGE(0, 0);
  STAGE(1, 1);
  STAGE(2, 2);
  STAGE(3, 3);

  for (int tt = 0; tt < NT; tt += 2) {
    if (tt + 4 < NT) { asm volatile("s_waitcnt vmcnt(8)" ::: "memory"); }
    else             { asm volatile("s_waitcnt vmcnt(0)" ::: "memory"); }
    __builtin_amdgcn_s_barrier();
    asm volatile("" ::: "memory");

    COMPUTE(tt & 3);
    COMPUTE((tt + 1) & 3);

    asm volatile("s_waitcnt lgkmcnt(0)" ::: "memory");
    __builtin_amdgcn_s_barrier();
    asm volatile("" ::: "memory");
    if (tt + 4 < NT) {
      STAGE(tt + 4, (tt + 4) & 3);
      if (tt + 5 < NT) STAGE(tt + 5, (tt + 5) & 3);
    }
  }
#undef COMPUTE
#undef STAGE

  const int crow = m0 + wr*64 + (l >> 4) * 4;
  const int ccol0 = n0 + wc*64 + fr;
  #pragma unroll
  for (int m = 0; m < 4; ++m) {
    #pragma unroll
    for (int n = 0; n < 4; ++n) {
      int colo = ccol0 + n*16;
      if (colo < N) {
        if (OUT_F16) {
          unsigned short* cp = (unsigned short*)Cv + (size_t)(crow + m*16)*N + colo;
          #pragma unroll
          for (int jj = 0; jj < 4; ++jj) cp[(size_t)jj*N] = f2h(acc[m][n][jj]);
        } else {
          float* cp = (float*)Cv + (size_t)(crow + m*16)*N + colo;
          #pragma unroll
          for (int jj = 0; jj < 4; ++jj) cp[(size_t)jj*N] = acc[m][n][jj] * Sc[crow + m*16 + jj];
        }
      }
    }
  }
}

// ---------- fused dt + per-chunk cumsum ----------
__global__ __launch_bounds__(64) void dtacum_kernel(const unsigned short* __restrict__ zx,
    const float* __restrict__ dt_bias, const float* __restrict__ A_log,
    float* __restrict__ dt, float* __restrict__ A_cum) {
  int blk = blockIdx.x;                             // (b*32+h)*32+c
  int c = blk & 31, h = (blk >> 5) & 31, b = blk >> 10;
  int l = threadIdx.x;
  int row = b*LSEQ + c*CHUNK + l;
  float v = h2f(zx[(size_t)row*DPROJ + (2*D_INNER + 2*D_STATE) + h]) + dt_bias[h];
  float dtv = softplusf(v);
  dt[row*NHEADS + h] = dtv;
  float val = -expf(A_log[h]) * dtv;
  #pragma unroll
  for (int off = 1; off < 64; off <<= 1) {
    float nv = __shfl_up(val, off, 64);
    if (l >= off) val += nv;
  }
  A_cum[blk*64 + l] = val;
}

// causal depthwise conv (K=4) + bias + silu; fp16 in/out; 8 rows x 4 channels per thread
__global__ __launch_bounds__(256) void conv8_kernel(const unsigned short* __restrict__ zx,
    const float* __restrict__ w, const float* __restrict__ bias, unsigned short* __restrict__ xBC) {
  int idx = blockIdx.x*256 + threadIdx.x;           // over (BL/8) * (CONV_DIM/4)
  if (idx >= (BL/8)*(CONV_DIM/4)) return;
  int c4  = idx % (CONV_DIM/4);
  int rb  = idx / (CONV_DIM/4);
  int ch  = c4 * 4;
  int row0 = rb * 8;
  int l0   = row0 & (LSEQ-1);
  float4 r[11];
  #pragma unroll
  for (int jj=0;jj<11;++jj){
    int li = l0 + jj - 3;
    if (li >= 0) {
      ushort4 v = *(const ushort4*)&zx[(size_t)(row0 + jj - 3)*DPROJ + D_INNER + ch];
      r[jj] = make_float4(h2f(v.x), h2f(v.y), h2f(v.z), h2f(v.w));
    } else r[jj] = make_float4(0.f,0.f,0.f,0.f);
  }
  float4 wv[4];
  #pragma unroll
  for (int c=0;c<4;++c) wv[c] = *(const float4*)&w[(ch+c)*4];
  float4 bv = *(const float4*)&bias[ch];
  #pragma unroll
  for (int j=0;j<8;++j){
    float4 acc = bv;
    acc.x += wv[0].x*r[j].x + wv[0].y*r[j+1].x + wv[0].z*r[j+2].x + wv[0].w*r[j+3].x;
    acc.y += wv[1].x*r[j].y + wv[1].y*r[j+1].y + wv[1].z*r[j+2].y + wv[1].w*r[j+3].y;
    acc.z += wv[2].x*r[j].z + wv[2].y*r[j+1].z + wv[2].z*r[j+2].z + wv[2].w*r[j+3].z;
    acc.w += wv[3].x*r[j].w + wv[3].y*r[j+1].w + wv[3].z*r[j+2].w + wv[3].w*r[j+3].w;
    ushort4 o; o.x=f2h(siluf(acc.x)); o.y=f2h(siluf(acc.y)); o.z=f2h(siluf(acc.z)); o.w=f2h(siluf(acc.w));
    *(ushort4*)&xBC[(size_t)(row0+j)*CONV_DIM + ch] = o;
  }
}

// G[b,c][l][s] = sum_n C[l,n] * B[s,n]; 4 blocks per (b,c); fp16 G out
__global__ __launch_bounds__(256) void g_kernel(const unsigned short* __restrict__ xBC,
                                                unsigned short* __restrict__ G) {
  int blk = blockIdx.x >> 2;                        // b*32 + c
  int lq  = blockIdx.x & 3;
  int b = blk >> 5, c = blk & 31;
  __shared__ float Bsh[64][129];
  int t = threadIdx.x;
  int row0 = b*LSEQ + c*CHUNK;
  #pragma unroll
  for (int j=0;j<8;++j){
    int e0 = (j*256 + t)*4;                         // 0..8191
    int s = e0 >> 7, n = e0 & 127;
    ushort4 v = *(const ushort4*)&xBC[(size_t)(row0+s)*CONV_DIM + D_INNER + n];
    Bsh[s][n+0] = h2f(v.x); Bsh[s][n+1] = h2f(v.y);
    Bsh[s][n+2] = h2f(v.z); Bsh[s][n+3] = h2f(v.w);
  }
  __syncthreads();
  int l = lq*16 + (t >> 4), s0 = (t & 15) * 4;
  const unsigned short* Cp = &xBC[(size_t)(row0+l)*CONV_DIM + D_INNER + D_STATE];
  float acc[4] = {};
  #pragma unroll 4
  for (int n4=0;n4<32;++n4){
    ushort4 cv4 = *(const ushort4*)&Cp[n4*4];
    float cv[4] = { h2f(cv4.x), h2f(cv4.y), h2f(cv4.z), h2f(cv4.w) };
    #pragma unroll
    for (int kk=0;kk<4;++kk){
      #pragma unroll
      for (int j=0;j<4;++j) acc[j] += cv[kk] * Bsh[s0+j][n4*4+kk];
    }
  }
  unsigned short* Gp = &G[(size_t)blk*4096 + l*64 + s0];
  ushort4 o; o.x=f2h(acc[0]); o.y=f2h(acc[1]); o.z=f2h(acc[2]); o.w=f2h(acc[3]);
  *(ushort4*)Gp = o;
}

// ---------- MFMA states (fp16 out, vectorized staging) ----------
__global__ __launch_bounds__(256) void states_mfma(const unsigned short* __restrict__ xBC,
    const float* __restrict__ dt, const float* __restrict__ A_cum, unsigned short* __restrict__ states) {
  int blk = blockIdx.x;                             // (b*32+c)*32+h
  int h = blk & 31, c = (blk>>5)&31, b = blk>>10;
  __shared__ _Float16 Bt[128][72];                  // [n][s]
  __shared__ _Float16 xdT[64][72];                  // [p][s]
  __shared__ float Ac[64], dtl[64];
  int t = threadIdx.x;
  int wid = t >> 6, ln = t & 63;
  int row0 = b*LSEQ + c*CHUNK;
  if (t < 64){ Ac[t] = A_cum[((b*32+h)*32 + c)*64 + t]; dtl[t] = dt[(row0+t)*NHEADS + h]; }
  __syncthreads();
  float AcL = Ac[63];
  #pragma unroll
  for (int j=0;j<8;++j){
    int e0 = (j*256+t)*4;                           // 0..8191
    int s = e0 >> 7, n = e0 & 127;
    ushort4 v = *(const ushort4*)&xBC[(size_t)(row0+s)*CONV_DIM + D_INNER + n];
    Bt[n+0][s] = h2h(v.x); Bt[n+1][s] = h2h(v.y);
    Bt[n+2][s] = h2h(v.z); Bt[n+3][s] = h2h(v.w);
  }
  #pragma unroll
  for (int j=0;j<4;++j){
    int e0 = (j*256+t)*4;                           // 0..4095
    int s = e0 >> 6, p = e0 & 63;
    float sc = dtl[s] * expf(AcL - Ac[s]);
    ushort4 v = *(const ushort4*)&xBC[(size_t)(row0+s)*CONV_DIM + h*HEADDIM + p];
    xdT[p+0][s] = (_Float16)(h2f(v.x)*sc);
    xdT[p+1][s] = (_Float16)(h2f(v.y)*sc);
    xdT[p+2][s] = (_Float16)(h2f(v.z)*sc);
    xdT[p+3][s] = (_Float16)(h2f(v.w)*sc);
  }
  __syncthreads();
  const int fr = ln & 15, fk = (ln >> 4) * 8;
  f32x4 acc[4][2] = {};
  #pragma unroll
  for (int ks = 0; ks < 2; ++ks){
    half8 a[4], bb[2];
    #pragma unroll
    for (int pt=0;pt<4;++pt) a[pt] = *(const half8*)&xdT[pt*16+fr][ks*32+fk];
    #pragma unroll
    for (int nt=0;nt<2;++nt) bb[nt] = *(const half8*)&Bt[(wid*2+nt)*16+fr][ks*32+fk];
    #pragma unroll
    for (int pt=0;pt<4;++pt)
      #pragma unroll
      for (int nt=0;nt<2;++nt)
        acc[pt][nt] = __builtin_amdgcn_mfma_f32_16x16x32_f16(a[pt], bb[nt], acc[pt][nt], 0, 0, 0);
  }
  unsigned short* Sp = &states[(size_t)blk*8192];
  #pragma unroll
  for (int pt=0;pt<4;++pt){
    int p0 = pt*16 + (ln>>4)*4;
    #pragma unroll
    for (int nt=0;nt<2;++nt){
      int n = (wid*2+nt)*16 + fr;
      #pragma unroll
      for (int j=0;j<4;++j) Sp[(p0+j)*128 + n] = f2h(acc[pt][nt][j]);
    }
  }
}

// inter-chunk scan: prefetch all chunk values, then serial VALU recurrence + stores
__global__ __launch_bounds__(256) void scan_kernel(const float* __restrict__ A_cum,
                                                   unsigned short* __restrict__ states) {
  int g  = blockIdx.x & 7;
  int bh = blockIdx.x >> 3;
  int b = bh >> 5, h = bh & 31;
  int t = threadIdx.x;
  int off = g*1024 + t*4;
  ushort4 tmp[NCHUNK];
  float dec[NCHUNK];
  #pragma unroll
  for (int c=0;c<NCHUNK;++c){
    tmp[c] = *(const ushort4*)&states[(size_t)((b*32+c)*32 + h)*8192 + off];
    dec[c] = A_cum[((b*32+h)*32 + c)*64 + 63];
  }
  float s0=0.f, s1=0.f, s2=0.f, s3=0.f;
  #pragma unroll
  for (int c=0;c<NCHUNK;++c){
    float d = expf(dec[c]);
    ushort4 o; o.x=f2h(s0); o.y=f2h(s1); o.z=f2h(s2); o.w=f2h(s3);
    *(ushort4*)&states[(size_t)((b*32+c)*32 + h)*8192 + off] = o;
    s0 = s0*d + h2f(tmp[c].x);
    s1 = s1*d + h2f(tmp[c].y);
    s2 = s2*d + h2f(tmp[c].z);
    s3 = s3*d + h2f(tmp[c].w);
  }
}

// ---------- MFMA Y (vectorized staging, fp16 G) ----------
__global__ __launch_bounds__(256) void y_mfma(const unsigned short* __restrict__ xBC,
    const unsigned short* __restrict__ zx, const float* __restrict__ dt,
    const float* __restrict__ A_cum, const unsigned short* __restrict__ G,
    const unsigned short* __restrict__ states, const float* __restrict__ Dp,
    unsigned short* __restrict__ y_pre) {
  int blk = blockIdx.x;                             // (b*32+c)*32+h
  int h = blk & 31, c = (blk>>5)&31, b = blk>>10;
  __shared__ _Float16 Cl[64][136];
  __shared__ _Float16 Sin[64][136];
  __shared__ _Float16 Ms[64][72];
  __shared__ _Float16 xdT[64][72];
  __shared__ float Ac[64], dtl[64];
  int t = threadIdx.x;
  int wid = t >> 6, ln = t & 63;
  int row0 = b*LSEQ + c*CHUNK;
  if (t < 64){ Ac[t] = A_cum[((b*32+h)*32 + c)*64 + t]; dtl[t] = dt[(row0+t)*NHEADS + h]; }
  __syncthreads();
  #pragma unroll
  for (int j=0;j<8;++j){
    int e0 = (j*256+t)*4; int l = e0>>7, n = e0&127;
    float sc = expf(Ac[l]);
    ushort4 v = *(const ushort4*)&xBC[(size_t)(row0+l)*CONV_DIM + D_INNER + D_STATE + n];
    half4 hv = { (_Float16)(h2f(v.x)*sc), (_Float16)(h2f(v.y)*sc),
                 (_Float16)(h2f(v.z)*sc), (_Float16)(h2f(v.w)*sc) };
    *(half4*)&Cl[l][n] = hv;
  }
  {
    const unsigned short* Sg = &states[(size_t)blk*8192];
    #pragma unroll
    for (int j=0;j<8;++j){
      int elem = (j*256+t)*4; int p = elem>>7, n = elem&127;
      ushort4 v = *(const ushort4*)&Sg[elem];
      half4 hv = { h2h(v.x), h2h(v.y), h2h(v.z), h2h(v.w) };
      *(half4*)&Sin[p][n] = hv;
    }
  }
  #pragma unroll
  for (int j=0;j<4;++j){
    int e0 = (j*256+t)*4; int s = e0>>6, p = e0&63;
    float sc = dtl[s];
    ushort4 v = *(const ushort4*)&xBC[(size_t)(row0+s)*CONV_DIM + h*HEADDIM + p];
    xdT[p+0][s] = (_Float16)(h2f(v.x)*sc);
    xdT[p+1][s] = (_Float16)(h2f(v.y)*sc);
    xdT[p+2][s] = (_Float16)(h2f(v.z)*sc);
    xdT[p+3][s] = (_Float16)(h2f(v.w)*sc);
  }
  {
    const unsigned short* Gp = &G[(size_t)(b*32+c)*4096];
    #pragma unroll
    for (int j=0;j<4;++j){
      int e0 = (j*256+t)*4; int l = e0>>6, s = e0&63;
      ushort4 gv = *(const ushort4*)&Gp[e0];
      float al = Ac[l];
      Ms[l][s+0] = (s+0 <= l) ? (_Float16)(h2f(gv.x) * expf(al-Ac[s+0])) : (_Float16)0.f;
      Ms[l][s+1] = (s+1 <= l) ? (_Float16)(h2f(gv.y) * expf(al-Ac[s+1])) : (_Float16)0.f;
      Ms[l][s+2] = (s+2 <= l) ? (_Float16)(h2f(gv.z) * expf(al-Ac[s+2])) : (_Float16)0.f;
      Ms[l][s+3] = (s+3 <= l) ? (_Float16)(h2f(gv.w) * expf(al-Ac[s+3])) : (_Float16)0.f;
    }
  }
  __syncthreads();
  const int wr = wid >> 1, wc = wid & 1;
  const int fr = ln & 15, fk = (ln >> 4) * 8;
  f32x4 acc[2][2] = {};
  #pragma unroll
  for (int ks = 0; ks < 4; ++ks){
    half8 a[2], bb[2];
    #pragma unroll
    for (int lt=0;lt<2;++lt) a[lt] = *(const half8*)&Cl[(wr*2+lt)*16+fr][ks*32+fk];
    #pragma unroll
    for (int pt=0;pt<2;++pt) bb[pt] = *(const half8*)&Sin[(wc*2+pt)*16+fr][ks*32+fk];
    #pragma unroll
    for (int lt=0;lt<2;++lt)
      #pragma unroll
      for (int pt=0;pt<2;++pt)
        acc[lt][pt] = __builtin_amdgcn_mfma_f32_16x16x32_f16(a[lt], bb[pt], acc[lt][pt], 0, 0, 0);
  }
  #pragma unroll
  for (int ks = 0; ks < 2; ++ks){
    half8 a[2], bb[2];
    #pragma unroll
    for (int lt=0;lt<2;++lt) a[lt] = *(const half8*)&Ms[(wr*2+lt)*16+fr][ks*32+fk];
    #pragma unroll
    for (int pt=0;pt<2;++pt) bb[pt] = *(const half8*)&xdT[(wc*2+pt)*16+fr][ks*32+fk];
    #pragma unroll
    for (int lt=0;lt<2;++lt)
      #pragma unroll
      for (int pt=0;pt<2;++pt)
        acc[lt][pt] = __builtin_amdgcn_mfma_f32_16x16x32_f16(a[lt], bb[pt], acc[lt][pt], 0, 0, 0);
  }
  float Dh = Dp[h];
  #pragma unroll
  for (int lt=0;lt<2;++lt){
    int l0 = (wr*2+lt)*16 + (ln>>4)*4;
    #pragma unroll
    for (int pt=0;pt<2;++pt){
      int p = (wc*2+pt)*16 + fr;
      #pragma unroll
      for (int j=0;j<4;++j){
        int grow = row0 + l0 + j;
        float x = h2f(xBC[(size_t)grow*CONV_DIM + h*HEADDIM + p]);
        float z = h2f(zx[(size_t)grow*DPROJ + h*HEADDIM + p]);
        y_pre[(size_t)grow*D_INNER + h*HEADDIM + p] = f2h((acc[lt][pt][j] + x*Dh) * siluf(z));
      }
    }
  }
}

// per-row RMS scale: sc[row] = rsqrt(mean(ypre^2) + eps)
__global__ __launch_bounds__(256) void rowsc_kernel(const unsigned short* __restrict__ y,
                                                    float* __restrict__ sc) {
  int row = blockIdx.x;
  int t = threadIdx.x;
  const unsigned short* yr = y + (size_t)row*D_INNER + t*8;
  ushort4 a = *(const ushort4*)yr;
  ushort4 bq = *(const ushort4*)(yr+4);
  float ss = 0.f;
  float v;
  v=h2f(a.x); ss+=v*v; v=h2f(a.y); ss+=v*v; v=h2f(a.z); ss+=v*v; v=h2f(a.w); ss+=v*v;
  v=h2f(bq.x); ss+=v*v; v=h2f(bq.y); ss+=v*v; v=h2f(bq.z); ss+=v*v; v=h2f(bq.w); ss+=v*v;
  #pragma unroll
  for (int off=32; off>0; off>>=1) ss += __shfl_down(ss, off, 64);
  __shared__ float wsum[4];
  int wid = t >> 6, lane = t & 63;
  if (lane == 0) wsum[wid] = ss;
  __syncthreads();
  if (t == 0) sc[row] = rsqrtf((wsum[0]+wsum[1]+wsum[2]+wsum[3])/D_INNER + EPSF);
}

extern "C" void kernel_launch(void* const* d_in, const int* in_sizes, int n_in,
                              void* d_out, int out_size, void* d_ws, size_t ws_size,
                              hipStream_t stream) {
  const float* u       = (const float*)d_in[0];
  const float* W_in    = (const float*)d_in[1];
  const float* conv_w  = (const float*)d_in[2];
  const float* conv_b  = (const float*)d_in[3];
  const float* dt_bias = (const float*)d_in[4];
  const float* A_log   = (const float*)d_in[5];
  const float* Dp      = (const float*)d_in[6];
  const float* norm_w  = (const float*)d_in[7];
  const float* W_out   = (const float*)d_in[8];
  float* out = (float*)d_out;

  char* w = (char*)d_ws;
  unsigned short* zx_h   = (unsigned short*)w;  w += (size_t)BL*DPROJ*2;
  unsigned short* xBC_h  = (unsigned short*)w;  w += (size_t)BL*CONV_DIM*2;
  unsigned short* ypre_h = (unsigned short*)w;  w += (size_t)BL*D_INNER*2;
  unsigned short* u_h    = (unsigned short*)w;  w += (size_t)BL*D_MODEL*2;
  unsigned short* Win_h  = (unsigned short*)w;  w += (size_t)NPAD1*D_MODEL*2;
  unsigned short* Wg_h   = (unsigned short*)w;  w += (size_t)D_MODEL*D_INNER*2;
  unsigned short* states = (unsigned short*)w;  w += (size_t)B_SZ*NCHUNK*NHEADS*HEADDIM*D_STATE*2;
  unsigned short* G      = (unsigned short*)w;  w += (size_t)B_SZ*NCHUNK*CHUNK*CHUNK*2;
  float* dt     = (float*)w;  w += (size_t)BL*NHEADS*4;
  float* A_cum  = (float*)w;  w += (size_t)B_SZ*NHEADS*NCHUNK*CHUNK*4;
  float* sc     = (float*)w;  w += (size_t)BL*4;

  // 0) all converts in one launch (Wg = W_out * norm_w, RMS fold)
  cvt_all<<<(NCVT+255)/256, 256, 0, stream>>>(u, W_in, W_out, norm_w, u_h, Win_h, Wg_h);
  // 1) zxbcdt = u @ W_in.T  (fp16 out; includes dt logit columns)
  gemm_f16_pipe<1><<<dim3(NPAD1/128, BL/128), 256, 0, stream>>>(u_h, Win_h, zx_h, nullptr, DPROJ, D_MODEL);
  // 2) dt + per-chunk cumsum (fused, shfl prefix)
  dtacum_kernel<<<B_SZ*NHEADS*NCHUNK, 64, 0, stream>>>(zx_h, dt_bias, A_log, dt, A_cum);
  // 3) depthwise conv + silu (fp16 in/out)
  conv8_kernel<<<((BL/8)*(CONV_DIM/4)+255)/256, 256, 0, stream>>>(zx_h, conv_w, conv_b, xBC_h);
  // 4) G = C B^T per (b,c), fp16 out
  g_kernel<<<B_SZ*NCHUNK*4, 256, 0, stream>>>(xBC_h, G);
  // 5) per-chunk states (MFMA, fp16 out)
  states_mfma<<<B_SZ*NCHUNK*NHEADS, 256, 0, stream>>>(xBC_h, dt, A_cum, states);
  // 6) inter-chunk scan (prefetch-all + serial recurrence), 8-way split
  scan_kernel<<<B_SZ*NHEADS*8, 256, 0, stream>>>(A_cum, states);
  // 7) Y (MFMA), fp16 out (unnormalized)
  y_mfma<<<B_SZ*NCHUNK*NHEADS, 256, 0, stream>>>(xBC_h, zx_h, dt, A_cum, G, states, Dp, ypre_h);
  // 8) per-row RMS scale
  rowsc_kernel<<<BL, 256, 0, stream>>>(ypre_h, sc);
  // 9) out = diag(sc) * (ypre @ (W_out*norm_w).T)  (fp32 out, scaled epilogue)
  gemm_f16_pipe<0><<<dim3(D_MODEL/128, BL/128), 256, 0, stream>>>(ypre_h, Wg_h, out, sc, D_MODEL, D_INNER);
}

// Round 16
// 185.199 us; speedup vs baseline: 1.1623x; 1.0124x over previous
//
#include <hip/hip_runtime.h>
#include <hip/hip_bf16.h>
#include <math.h>

#define D_MODEL 1024
#define D_INNER 2048
#define D_STATE 128
#define NHEADS 32
#define HEADDIM 64
#define CHUNK 64
#define B_SZ 2
#define LSEQ 2048
#define BL (B_SZ*LSEQ)                              // 4096
#define DPROJ (2*D_INNER + 2*D_STATE + NHEADS)      // 4384
#define CONV_DIM (D_INNER + 2*D_STATE)              // 2304
#define NCHUNK (LSEQ/CHUNK)                         // 32
#define NPAD1 4480                                  // DPROJ padded to x128
#define EPSF 1e-5f

typedef __attribute__((ext_vector_type(8))) _Float16 half8;
typedef __attribute__((ext_vector_type(4))) _Float16 half4;
typedef __attribute__((ext_vector_type(4))) float f32x4;

__device__ __forceinline__ float siluf(float v){ return v / (1.0f + expf(-v)); }
__device__ __forceinline__ float softplusf(float v){ return v > 20.0f ? v : log1pf(expf(v)); }
__device__ __forceinline__ unsigned short f2h(float x){
  union { _Float16 h; unsigned short u; } v; v.h = (_Float16)x;
  return v.u;
}
__device__ __forceinline__ float h2f(unsigned short x){
  union { unsigned short u; _Float16 h; } v; v.u = x;
  return (float)v.h;
}
__device__ __forceinline__ _Float16 h2h(unsigned short x){
  union { unsigned short u; _Float16 h; } v; v.u = x;
  return v.h;
}

typedef const __attribute__((address_space(1))) void gvoid_t;
typedef __attribute__((address_space(3))) void lvoid_t;
__device__ __forceinline__ void gl_lds16(const void* gsrc, void* ldst) {
  gvoid_t* g = reinterpret_cast<gvoid_t*>((uintptr_t)gsrc);
  lvoid_t* l = reinterpret_cast<lvoid_t*>((unsigned int)(uintptr_t)ldst);
  __builtin_amdgcn_global_load_lds(g, l, 16, 0, 0);
}

#define NU4  (BL*D_MODEL/4)
#define NW4  (NPAD1*D_MODEL/4)
#define NWo4 (D_MODEL*D_INNER/4)
#define NCVT (NU4+NW4+NWo4)

// ---------- fused converters ----------
__global__ void cvt_all(const float* __restrict__ u, const float* __restrict__ W_in,
                        const float* __restrict__ W_out, const float* __restrict__ norm_w,
                        unsigned short* __restrict__ u_h, unsigned short* __restrict__ Win_h,
                        unsigned short* __restrict__ Wg_h) {
  int i = blockIdx.x*256 + threadIdx.x;
  if (i >= NCVT) return;
  if (i < NU4) {
    float4 v = *(const float4*)(u + (size_t)i*4);
    ushort4 o; o.x=f2h(v.x); o.y=f2h(v.y); o.z=f2h(v.z); o.w=f2h(v.w);
    *(ushort4*)(u_h + (size_t)i*4) = o;
  } else if (i < NU4 + NW4) {
    int q = i - NU4;
    int row = q / (D_MODEL/4);
    ushort4 o; o.x=0; o.y=0; o.z=0; o.w=0;
    if (row < DPROJ) {
      float4 v = *(const float4*)(W_in + (size_t)q*4);
      o.x=f2h(v.x); o.y=f2h(v.y); o.z=f2h(v.z); o.w=f2h(v.w);
    }
    *(ushort4*)(Win_h + (size_t)q*4) = o;
  } else {
    int q = i - NU4 - NW4;
    int colq = q % (D_INNER/4);
    float4 v = *(const float4*)(W_out + (size_t)q*4);
    float4 g = *(const float4*)(norm_w + (size_t)colq*4);
    ushort4 o; o.x=f2h(v.x*g.x); o.y=f2h(v.y*g.y); o.z=f2h(v.z*g.z); o.w=f2h(v.w*g.w);
    *(ushort4*)(Wg_h + (size_t)q*4) = o;
  }
}

// ---------- GEMM1: 128x128, 4 slots, 2 K-tiles per barrier pair, region-mapped ----------
template<int OUT_F16>
__global__ __launch_bounds__(256) void gemm_f16_pipe(const unsigned short* __restrict__ A,
    const unsigned short* __restrict__ W, void* __restrict__ Cv,
    const float* __restrict__ Sc, int N, int K) {
  __shared__ unsigned short lds[4*2*4096];          // 64 KB -> 2 blocks/CU
  const int t   = threadIdx.x;
  const int wid = t >> 6, l = t & 63;
  const int gx = gridDim.x, gy = gridDim.y;         // gy % 8 == 0
  int bid = blockIdx.y * gx + blockIdx.x;
  int k   = bid & 7;
  int j   = bid >> 3;
  int rpx = gy >> 3;
  int r   = j % rpx;
  int colIdx = j / rpx;
  int row = k*rpx + r;
  int col = (colIdx + k*(gx >> 3)) % gx;
  const int m0 = row * 128;
  const int n0 = col * 128;
  const int wr = wid >> 1, wc = wid & 1;
  const int fr = l & 15, cg = l >> 4;
  const int NT = K >> 5;

  int srow[2]; int scol[2];
  #pragma unroll
  for (int i=0;i<2;++i){
    int s = i*256 + t;
    int rr = s >> 2, c = s & 3;
    int sw = (rr + (rr>>2)) & 3;
    srow[i] = rr; scol[i] = (c ^ sw) * 8;
  }
  const unsigned short* Abase = A + (size_t)m0 * K;
  const unsigned short* Wbase = W + (size_t)n0 * K;

#define STAGE(tt, slot) { \
    int kk = (tt) << 5; \
    unsigned short* La = &lds[(slot)*8192]; \
    unsigned short* Lb = &lds[(slot)*8192 + 4096]; \
    gl_lds16(Abase + (size_t)srow[0]*K + kk + scol[0], (char*)La + (0*256+t)*16); \
    gl_lds16(Abase + (size_t)srow[1]*K + kk + scol[1], (char*)La + (1*256+t)*16); \
    gl_lds16(Wbase + (size_t)srow[0]*K + kk + scol[0], (char*)Lb + (0*256+t)*16); \
    gl_lds16(Wbase + (size_t)srow[1]*K + kk + scol[1], (char*)Lb + (1*256+t)*16); \
  }

#define COMPUTE(slot) { \
    const unsigned short* La = &lds[(slot)*8192]; \
    const unsigned short* Lb = &lds[(slot)*8192 + 4096]; \
    half8 af[4], bfv[4]; \
    _Pragma("unroll") \
    for (int m=0;m<4;++m){ \
      int rr = wr*64 + m*16 + fr; \
      int sw = (rr + (rr>>2)) & 3; \
      af[m] = *(const half8*)&La[(rr*4 + (cg ^ sw))*8]; \
    } \
    _Pragma("unroll") \
    for (int n=0;n<4;++n){ \
      int rr = wc*64 + n*16 + fr; \
      int sw = (rr + (rr>>2)) & 3; \
      bfv[n] = *(const half8*)&Lb[(rr*4 + (cg ^ sw))*8]; \
    } \
    __builtin_amdgcn_s_setprio(1); \
    _Pragma("unroll") \
    for (int m=0;m<4;++m) \
      _Pragma("unroll") \
      for (int n=0;n<4;++n) \
        acc[m][n] = __builtin_amdgcn_mfma_f32_16x16x32_f16(af[m], bfv[n], acc[m][n], 0, 0, 0); \
    __builtin_amdgcn_s_setprio(0); \
  }

  f32x4 acc[4][4] = {};
  STAGE(0, 0);
  STAGE(1, 1);
  STAGE(2, 2);
  STAGE(3, 3);

  for (int tt = 0; tt < NT; tt += 2) {
    if (tt + 4 < NT) { asm volatile("s_waitcnt vmcnt(8)" ::: "memory"); }
    else             { asm volatile("s_waitcnt vmcnt(0)" ::: "memory"); }
    __builtin_amdgcn_s_barrier();
    asm volatile("" ::: "memory");

    COMPUTE(tt & 3);
    COMPUTE((tt + 1) & 3);

    asm volatile("s_waitcnt lgkmcnt(0)" ::: "memory");
    __builtin_amdgcn_s_barrier();
    asm volatile("" ::: "memory");
    if (tt + 4 < NT) {
      STAGE(tt + 4, (tt + 4) & 3);
      if (tt + 5 < NT) STAGE(tt + 5, (tt + 5) & 3);
    }
  }
#undef COMPUTE
#undef STAGE

  const int crow = m0 + wr*64 + (l >> 4) * 4;
  const int ccol0 = n0 + wc*64 + fr;
  #pragma unroll
  for (int m = 0; m < 4; ++m) {
    #pragma unroll
    for (int n = 0; n < 4; ++n) {
      int colo = ccol0 + n*16;
      if (colo < N) {
        if (OUT_F16) {
          unsigned short* cp = (unsigned short*)Cv + (size_t)(crow + m*16)*N + colo;
          #pragma unroll
          for (int jj = 0; jj < 4; ++jj) cp[(size_t)jj*N] = f2h(acc[m][n][jj]);
        } else {
          float* cp = (float*)Cv + (size_t)(crow + m*16)*N + colo;
          #pragma unroll
          for (int jj = 0; jj < 4; ++jj) cp[(size_t)jj*N] = acc[m][n][jj] * Sc[crow + m*16 + jj];
        }
      }
    }
  }
}

// ---------- GEMM2: 64x128 tile, 4 waves, 48 KB LDS -> 3 blocks/CU, pair schedule ----------
// C[m,n] = Sc[m] * sum_k A[m,k]*W[n,k].  grid (N/128, M/64), fp32 out.
__global__ __launch_bounds__(256) void gemm_f16_64(const unsigned short* __restrict__ A,
    const unsigned short* __restrict__ W, float* __restrict__ C,
    const float* __restrict__ Sc, int N, int K) {
  __shared__ unsigned short lds[4*6144];            // 4 slots x 12KB = 48KB
  const int t   = threadIdx.x;
  const int wid = t >> 6, l = t & 63;
  const int gx = gridDim.x, gy = gridDim.y;         // 8 x 64
  int bid = blockIdx.y * gx + blockIdx.x;
  int k   = bid & 7;
  int j   = bid >> 3;
  int rpx = gy >> 3;                                // 8
  int r   = j % rpx;
  int colIdx = j / rpx;
  const int m0 = (k*rpx + r) * 64;
  const int n0 = ((colIdx + k*(gx >> 3)) % gx) * 128;
  const int fr = l & 15, cg = l >> 4;
  const int NT = K >> 5;                            // 64 (even)

  // staging: granule t -> A row t>>2 and B row t>>2; granule t+256 -> B row 64+(t>>2)
  const int srw  = t >> 2;
  const int sw_  = (srw + (srw>>2)) & 3;            // sw(r) == sw(r+64)
  const int scl  = ((t & 3) ^ sw_) * 8;
  const unsigned short* Abase = A + (size_t)m0 * K;
  const unsigned short* Wbase = W + (size_t)n0 * K;

#define STG64(tt, slot) { \
    int kk = (tt) << 5; \
    char* Ls = (char*)lds + (slot)*12288; \
    gl_lds16(Abase + (size_t)srw*K + kk + scl,        Ls + t*16); \
    gl_lds16(Wbase + (size_t)srw*K + kk + scl,        Ls + 4096 + t*16); \
    gl_lds16(Wbase + (size_t)(64+srw)*K + kk + scl,   Ls + 4096 + (256+t)*16); \
  }

#define CMP64(slot) { \
    const unsigned short* La = &lds[(slot)*6144]; \
    const unsigned short* Lb = &lds[(slot)*6144 + 2048]; \
    half8 af[4], bfv[2]; \
    _Pragma("unroll") \
    for (int m=0;m<4;++m){ \
      int rr = m*16 + fr; \
      int sw = (rr + (rr>>2)) & 3; \
      af[m] = *(const half8*)&La[(rr*4 + (cg ^ sw))*8]; \
    } \
    _Pragma("unroll") \
    for (int n=0;n<2;++n){ \
      int rr = wid*32 + n*16 + fr; \
      int sw = (rr + (rr>>2)) & 3; \
      bfv[n] = *(const half8*)&Lb[(rr*4 + (cg ^ sw))*8]; \
    } \
    __builtin_amdgcn_s_setprio(1); \
    _Pragma("unroll") \
    for (int m=0;m<4;++m) \
      _Pragma("unroll") \
      for (int n=0;n<2;++n) \
        acc[m][n] = __builtin_amdgcn_mfma_f32_16x16x32_f16(af[m], bfv[n], acc[m][n], 0, 0, 0); \
    __builtin_amdgcn_s_setprio(0); \
  }

  f32x4 acc[4][2] = {};
  STG64(0, 0);
  STG64(1, 1);
  STG64(2, 2);
  STG64(3, 3);

  for (int tt = 0; tt < NT; tt += 2) {
    if (tt + 4 < NT) { asm volatile("s_waitcnt vmcnt(6)" ::: "memory"); }
    else             { asm volatile("s_waitcnt vmcnt(0)" ::: "memory"); }
    __builtin_amdgcn_s_barrier();
    asm volatile("" ::: "memory");

    CMP64(tt & 3);
    CMP64((tt + 1) & 3);

    asm volatile("s_waitcnt lgkmcnt(0)" ::: "memory");
    __builtin_amdgcn_s_barrier();
    asm volatile("" ::: "memory");
    if (tt + 4 < NT) {
      STG64(tt + 4, (tt + 4) & 3);
      if (tt + 5 < NT) STG64(tt + 5, (tt + 5) & 3);
    }
  }
#undef CMP64
#undef STG64

  const int crow = m0 + cg * 4;
  const int ccol0 = n0 + wid*32 + fr;
  #pragma unroll
  for (int m = 0; m < 4; ++m) {
    #pragma unroll
    for (int n = 0; n < 2; ++n) {
      int colo = ccol0 + n*16;
      float* cp = C + (size_t)(crow + m*16)*N + colo;
      #pragma unroll
      for (int jj = 0; jj < 4; ++jj) cp[(size_t)jj*N] = acc[m][n][jj] * Sc[crow + m*16 + jj];
    }
  }
}

// ---------- fused dt + per-chunk cumsum ----------
__global__ __launch_bounds__(64) void dtacum_kernel(const unsigned short* __restrict__ zx,
    const float* __restrict__ dt_bias, const float* __restrict__ A_log,
    float* __restrict__ dt, float* __restrict__ A_cum) {
  int blk = blockIdx.x;                             // (b*32+h)*32+c
  int c = blk & 31, h = (blk >> 5) & 31, b = blk >> 10;
  int l = threadIdx.x;
  int row = b*LSEQ + c*CHUNK + l;
  float v = h2f(zx[(size_t)row*DPROJ + (2*D_INNER + 2*D_STATE) + h]) + dt_bias[h];
  float dtv = softplusf(v);
  dt[row*NHEADS + h] = dtv;
  float val = -expf(A_log[h]) * dtv;
  #pragma unroll
  for (int off = 1; off < 64; off <<= 1) {
    float nv = __shfl_up(val, off, 64);
    if (l >= off) val += nv;
  }
  A_cum[blk*64 + l] = val;
}

// causal depthwise conv (K=4) + bias + silu; fp16 in/out; 8 rows x 4 channels per thread
__global__ __launch_bounds__(256) void conv8_kernel(const unsigned short* __restrict__ zx,
    const float* __restrict__ w, const float* __restrict__ bias, unsigned short* __restrict__ xBC) {
  int idx = blockIdx.x*256 + threadIdx.x;           // over (BL/8) * (CONV_DIM/4)
  if (idx >= (BL/8)*(CONV_DIM/4)) return;
  int c4  = idx % (CONV_DIM/4);
  int rb  = idx / (CONV_DIM/4);
  int ch  = c4 * 4;
  int row0 = rb * 8;
  int l0   = row0 & (LSEQ-1);
  float4 r[11];
  #pragma unroll
  for (int jj=0;jj<11;++jj){
    int li = l0 + jj - 3;
    if (li >= 0) {
      ushort4 v = *(const ushort4*)&zx[(size_t)(row0 + jj - 3)*DPROJ + D_INNER + ch];
      r[jj] = make_float4(h2f(v.x), h2f(v.y), h2f(v.z), h2f(v.w));
    } else r[jj] = make_float4(0.f,0.f,0.f,0.f);
  }
  float4 wv[4];
  #pragma unroll
  for (int c=0;c<4;++c) wv[c] = *(const float4*)&w[(ch+c)*4];
  float4 bv = *(const float4*)&bias[ch];
  #pragma unroll
  for (int j=0;j<8;++j){
    float4 acc = bv;
    acc.x += wv[0].x*r[j].x + wv[0].y*r[j+1].x + wv[0].z*r[j+2].x + wv[0].w*r[j+3].x;
    acc.y += wv[1].x*r[j].y + wv[1].y*r[j+1].y + wv[1].z*r[j+2].y + wv[1].w*r[j+3].y;
    acc.z += wv[2].x*r[j].z + wv[2].y*r[j+1].z + wv[2].z*r[j+2].z + wv[2].w*r[j+3].z;
    acc.w += wv[3].x*r[j].w + wv[3].y*r[j+1].w + wv[3].z*r[j+2].w + wv[3].w*r[j+3].w;
    ushort4 o; o.x=f2h(siluf(acc.x)); o.y=f2h(siluf(acc.y)); o.z=f2h(siluf(acc.z)); o.w=f2h(siluf(acc.w));
    *(ushort4*)&xBC[(size_t)(row0+j)*CONV_DIM + ch] = o;
  }
}

// G[b,c][l][s] = sum_n C[l,n] * B[s,n]; 4 blocks per (b,c); fp16 G out
__global__ __launch_bounds__(256) void g_kernel(const unsigned short* __restrict__ xBC,
                                                unsigned short* __restrict__ G) {
  int blk = blockIdx.x >> 2;                        // b*32 + c
  int lq  = blockIdx.x & 3;
  int b = blk >> 5, c = blk & 31;
  __shared__ float Bsh[64][129];
  int t = threadIdx.x;
  int row0 = b*LSEQ + c*CHUNK;
  #pragma unroll
  for (int j=0;j<8;++j){
    int e0 = (j*256 + t)*4;                         // 0..8191
    int s = e0 >> 7, n = e0 & 127;
    ushort4 v = *(const ushort4*)&xBC[(size_t)(row0+s)*CONV_DIM + D_INNER + n];
    Bsh[s][n+0] = h2f(v.x); Bsh[s][n+1] = h2f(v.y);
    Bsh[s][n+2] = h2f(v.z); Bsh[s][n+3] = h2f(v.w);
  }
  __syncthreads();
  int l = lq*16 + (t >> 4), s0 = (t & 15) * 4;
  const unsigned short* Cp = &xBC[(size_t)(row0+l)*CONV_DIM + D_INNER + D_STATE];
  float acc[4] = {};
  #pragma unroll 4
  for (int n4=0;n4<32;++n4){
    ushort4 cv4 = *(const ushort4*)&Cp[n4*4];
    float cv[4] = { h2f(cv4.x), h2f(cv4.y), h2f(cv4.z), h2f(cv4.w) };
    #pragma unroll
    for (int kk=0;kk<4;++kk){
      #pragma unroll
      for (int j=0;j<4;++j) acc[j] += cv[kk] * Bsh[s0+j][n4*4+kk];
    }
  }
  unsigned short* Gp = &G[(size_t)blk*4096 + l*64 + s0];
  ushort4 o; o.x=f2h(acc[0]); o.y=f2h(acc[1]); o.z=f2h(acc[2]); o.w=f2h(acc[3]);
  *(ushort4*)Gp = o;
}

// ---------- MFMA states (fp16 out, vectorized staging) ----------
__global__ __launch_bounds__(256) void states_mfma(const unsigned short* __restrict__ xBC,
    const float* __restrict__ dt, const float* __restrict__ A_cum, unsigned short* __restrict__ states) {
  int blk = blockIdx.x;                             // (b*32+c)*32+h
  int h = blk & 31, c = (blk>>5)&31, b = blk>>10;
  __shared__ _Float16 Bt[128][72];                  // [n][s]
  __shared__ _Float16 xdT[64][72];                  // [p][s]
  __shared__ float Ac[64], dtl[64];
  int t = threadIdx.x;
  int wid = t >> 6, ln = t & 63;
  int row0 = b*LSEQ + c*CHUNK;
  if (t < 64){ Ac[t] = A_cum[((b*32+h)*32 + c)*64 + t]; dtl[t] = dt[(row0+t)*NHEADS + h]; }
  __syncthreads();
  float AcL = Ac[63];
  #pragma unroll
  for (int j=0;j<8;++j){
    int e0 = (j*256+t)*4;                           // 0..8191
    int s = e0 >> 7, n = e0 & 127;
    ushort4 v = *(const ushort4*)&xBC[(size_t)(row0+s)*CONV_DIM + D_INNER + n];
    Bt[n+0][s] = h2h(v.x); Bt[n+1][s] = h2h(v.y);
    Bt[n+2][s] = h2h(v.z); Bt[n+3][s] = h2h(v.w);
  }
  #pragma unroll
  for (int j=0;j<4;++j){
    int e0 = (j*256+t)*4;                           // 0..4095
    int s = e0 >> 6, p = e0 & 63;
    float sc = dtl[s] * expf(AcL - Ac[s]);
    ushort4 v = *(const ushort4*)&xBC[(size_t)(row0+s)*CONV_DIM + h*HEADDIM + p];
    xdT[p+0][s] = (_Float16)(h2f(v.x)*sc);
    xdT[p+1][s] = (_Float16)(h2f(v.y)*sc);
    xdT[p+2][s] = (_Float16)(h2f(v.z)*sc);
    xdT[p+3][s] = (_Float16)(h2f(v.w)*sc);
  }
  __syncthreads();
  const int fr = ln & 15, fk = (ln >> 4) * 8;
  f32x4 acc[4][2] = {};
  #pragma unroll
  for (int ks = 0; ks < 2; ++ks){
    half8 a[4], bb[2];
    #pragma unroll
    for (int pt=0;pt<4;++pt) a[pt] = *(const half8*)&xdT[pt*16+fr][ks*32+fk];
    #pragma unroll
    for (int nt=0;nt<2;++nt) bb[nt] = *(const half8*)&Bt[(wid*2+nt)*16+fr][ks*32+fk];
    #pragma unroll
    for (int pt=0;pt<4;++pt)
      #pragma unroll
      for (int nt=0;nt<2;++nt)
        acc[pt][nt] = __builtin_amdgcn_mfma_f32_16x16x32_f16(a[pt], bb[nt], acc[pt][nt], 0, 0, 0);
  }
  unsigned short* Sp = &states[(size_t)blk*8192];
  #pragma unroll
  for (int pt=0;pt<4;++pt){
    int p0 = pt*16 + (ln>>4)*4;
    #pragma unroll
    for (int nt=0;nt<2;++nt){
      int n = (wid*2+nt)*16 + fr;
      #pragma unroll
      for (int j=0;j<4;++j) Sp[(p0+j)*128 + n] = f2h(acc[pt][nt][j]);
    }
  }
}

// inter-chunk scan: prefetch all chunk values, then serial VALU recurrence + stores
__global__ __launch_bounds__(256) void scan_kernel(const float* __restrict__ A_cum,
                                                   unsigned short* __restrict__ states) {
  int g  = blockIdx.x & 7;
  int bh = blockIdx.x >> 3;
  int b = bh >> 5, h = bh & 31;
  int t = threadIdx.x;
  int off = g*1024 + t*4;
  ushort4 tmp[NCHUNK];
  float dec[NCHUNK];
  #pragma unroll
  for (int c=0;c<NCHUNK;++c){
    tmp[c] = *(const ushort4*)&states[(size_t)((b*32+c)*32 + h)*8192 + off];
    dec[c] = A_cum[((b*32+h)*32 + c)*64 + 63];
  }
  float s0=0.f, s1=0.f, s2=0.f, s3=0.f;
  #pragma unroll
  for (int c=0;c<NCHUNK;++c){
    float d = expf(dec[c]);
    ushort4 o; o.x=f2h(s0); o.y=f2h(s1); o.z=f2h(s2); o.w=f2h(s3);
    *(ushort4*)&states[(size_t)((b*32+c)*32 + h)*8192 + off] = o;
    s0 = s0*d + h2f(tmp[c].x);
    s1 = s1*d + h2f(tmp[c].y);
    s2 = s2*d + h2f(tmp[c].z);
    s3 = s3*d + h2f(tmp[c].w);
  }
}

// ---------- MFMA Y (vectorized staging, fp16 G) ----------
__global__ __launch_bounds__(256) void y_mfma(const unsigned short* __restrict__ xBC,
    const unsigned short* __restrict__ zx, const float* __restrict__ dt,
    const float* __restrict__ A_cum, const unsigned short* __restrict__ G,
    const unsigned short* __restrict__ states, const float* __restrict__ Dp,
    unsigned short* __restrict__ y_pre) {
  int blk = blockIdx.x;                             // (b*32+c)*32+h
  int h = blk & 31, c = (blk>>5)&31, b = blk>>10;
  __shared__ _Float16 Cl[64][136];
  __shared__ _Float16 Sin[64][136];
  __shared__ _Float16 Ms[64][72];
  __shared__ _Float16 xdT[64][72];
  __shared__ float Ac[64], dtl[64];
  int t = threadIdx.x;
  int wid = t >> 6, ln = t & 63;
  int row0 = b*LSEQ + c*CHUNK;
  if (t < 64){ Ac[t] = A_cum[((b*32+h)*32 + c)*64 + t]; dtl[t] = dt[(row0+t)*NHEADS + h]; }
  __syncthreads();
  #pragma unroll
  for (int j=0;j<8;++j){
    int e0 = (j*256+t)*4; int l = e0>>7, n = e0&127;
    float sc = expf(Ac[l]);
    ushort4 v = *(const ushort4*)&xBC[(size_t)(row0+l)*CONV_DIM + D_INNER + D_STATE + n];
    half4 hv = { (_Float16)(h2f(v.x)*sc), (_Float16)(h2f(v.y)*sc),
                 (_Float16)(h2f(v.z)*sc), (_Float16)(h2f(v.w)*sc) };
    *(half4*)&Cl[l][n] = hv;
  }
  {
    const unsigned short* Sg = &states[(size_t)blk*8192];
    #pragma unroll
    for (int j=0;j<8;++j){
      int elem = (j*256+t)*4; int p = elem>>7, n = elem&127;
      ushort4 v = *(const ushort4*)&Sg[elem];
      half4 hv = { h2h(v.x), h2h(v.y), h2h(v.z), h2h(v.w) };
      *(half4*)&Sin[p][n] = hv;
    }
  }
  #pragma unroll
  for (int j=0;j<4;++j){
    int e0 = (j*256+t)*4; int s = e0>>6, p = e0&63;
    float sc = dtl[s];
    ushort4 v = *(const ushort4*)&xBC[(size_t)(row0+s)*CONV_DIM + h*HEADDIM + p];
    xdT[p+0][s] = (_Float16)(h2f(v.x)*sc);
    xdT[p+1][s] = (_Float16)(h2f(v.y)*sc);
    xdT[p+2][s] = (_Float16)(h2f(v.z)*sc);
    xdT[p+3][s] = (_Float16)(h2f(v.w)*sc);
  }
  {
    const unsigned short* Gp = &G[(size_t)(b*32+c)*4096];
    #pragma unroll
    for (int j=0;j<4;++j){
      int e0 = (j*256+t)*4; int l = e0>>6, s = e0&63;
      ushort4 gv = *(const ushort4*)&Gp[e0];
      float al = Ac[l];
      Ms[l][s+0] = (s+0 <= l) ? (_Float16)(h2f(gv.x) * expf(al-Ac[s+0])) : (_Float16)0.f;
      Ms[l][s+1] = (s+1 <= l) ? (_Float16)(h2f(gv.y) * expf(al-Ac[s+1])) : (_Float16)0.f;
      Ms[l][s+2] = (s+2 <= l) ? (_Float16)(h2f(gv.z) * expf(al-Ac[s+2])) : (_Float16)0.f;
      Ms[l][s+3] = (s+3 <= l) ? (_Float16)(h2f(gv.w) * expf(al-Ac[s+3])) : (_Float16)0.f;
    }
  }
  __syncthreads();
  const int wr = wid >> 1, wc = wid & 1;
  const int fr = ln & 15, fk = (ln >> 4) * 8;
  f32x4 acc[2][2] = {};
  #pragma unroll
  for (int ks = 0; ks < 4; ++ks){
    half8 a[2], bb[2];
    #pragma unroll
    for (int lt=0;lt<2;++lt) a[lt] = *(const half8*)&Cl[(wr*2+lt)*16+fr][ks*32+fk];
    #pragma unroll
    for (int pt=0;pt<2;++pt) bb[pt] = *(const half8*)&Sin[(wc*2+pt)*16+fr][ks*32+fk];
    #pragma unroll
    for (int lt=0;lt<2;++lt)
      #pragma unroll
      for (int pt=0;pt<2;++pt)
        acc[lt][pt] = __builtin_amdgcn_mfma_f32_16x16x32_f16(a[lt], bb[pt], acc[lt][pt], 0, 0, 0);
  }
  #pragma unroll
  for (int ks = 0; ks < 2; ++ks){
    half8 a[2], bb[2];
    #pragma unroll
    for (int lt=0;lt<2;++lt) a[lt] = *(const half8*)&Ms[(wr*2+lt)*16+fr][ks*32+fk];
    #pragma unroll
    for (int pt=0;pt<2;++pt) bb[pt] = *(const half8*)&xdT[(wc*2+pt)*16+fr][ks*32+fk];
    #pragma unroll
    for (int lt=0;lt<2;++lt)
      #pragma unroll
      for (int pt=0;pt<2;++pt)
        acc[lt][pt] = __builtin_amdgcn_mfma_f32_16x16x32_f16(a[lt], bb[pt], acc[lt][pt], 0, 0, 0);
  }
  float Dh = Dp[h];
  #pragma unroll
  for (int lt=0;lt<2;++lt){
    int l0 = (wr*2+lt)*16 + (ln>>4)*4;
    #pragma unroll
    for (int pt=0;pt<2;++pt){
      int p = (wc*2+pt)*16 + fr;
      #pragma unroll
      for (int j=0;j<4;++j){
        int grow = row0 + l0 + j;
        float x = h2f(xBC[(size_t)grow*CONV_DIM + h*HEADDIM + p]);
        float z = h2f(zx[(size_t)grow*DPROJ + h*HEADDIM + p]);
        y_pre[(size_t)grow*D_INNER + h*HEADDIM + p] = f2h((acc[lt][pt][j] + x*Dh) * siluf(z));
      }
    }
  }
}

// per-row RMS scale: sc[row] = rsqrt(mean(ypre^2) + eps)
__global__ __launch_bounds__(256) void rowsc_kernel(const unsigned short* __restrict__ y,
                                                    float* __restrict__ sc) {
  int row = blockIdx.x;
  int t = threadIdx.x;
  const unsigned short* yr = y + (size_t)row*D_INNER + t*8;
  ushort4 a = *(const ushort4*)yr;
  ushort4 bq = *(const ushort4*)(yr+4);
  float ss = 0.f;
  float v;
  v=h2f(a.x); ss+=v*v; v=h2f(a.y); ss+=v*v; v=h2f(a.z); ss+=v*v; v=h2f(a.w); ss+=v*v;
  v=h2f(bq.x); ss+=v*v; v=h2f(bq.y); ss+=v*v; v=h2f(bq.z); ss+=v*v; v=h2f(bq.w); ss+=v*v;
  #pragma unroll
  for (int off=32; off>0; off>>=1) ss += __shfl_down(ss, off, 64);
  __shared__ float wsum[4];
  int wid = t >> 6, lane = t & 63;
  if (lane == 0) wsum[wid] = ss;
  __syncthreads();
  if (t == 0) sc[row] = rsqrtf((wsum[0]+wsum[1]+wsum[2]+wsum[3])/D_INNER + EPSF);
}

extern "C" void kernel_launch(void* const* d_in, const int* in_sizes, int n_in,
                              void* d_out, int out_size, void* d_ws, size_t ws_size,
                              hipStream_t stream) {
  const float* u       = (const float*)d_in[0];
  const float* W_in    = (const float*)d_in[1];
  const float* conv_w  = (const float*)d_in[2];
  const float* conv_b  = (const float*)d_in[3];
  const float* dt_bias = (const float*)d_in[4];
  const float* A_log   = (const float*)d_in[5];
  const float* Dp      = (const float*)d_in[6];
  const float* norm_w  = (const float*)d_in[7];
  const float* W_out   = (const float*)d_in[8];
  float* out = (float*)d_out;

  char* w = (char*)d_ws;
  unsigned short* zx_h   = (unsigned short*)w;  w += (size_t)BL*DPROJ*2;
  unsigned short* xBC_h  = (unsigned short*)w;  w += (size_t)BL*CONV_DIM*2;
  unsigned short* ypre_h = (unsigned short*)w;  w += (size_t)BL*D_INNER*2;
  unsigned short* u_h    = (unsigned short*)w;  w += (size_t)BL*D_MODEL*2;
  unsigned short* Win_h  = (unsigned short*)w;  w += (size_t)NPAD1*D_MODEL*2;
  unsigned short* Wg_h   = (unsigned short*)w;  w += (size_t)D_MODEL*D_INNER*2;
  unsigned short* states = (unsigned short*)w;  w += (size_t)B_SZ*NCHUNK*NHEADS*HEADDIM*D_STATE*2;
  unsigned short* G      = (unsigned short*)w;  w += (size_t)B_SZ*NCHUNK*CHUNK*CHUNK*2;
  float* dt     = (float*)w;  w += (size_t)BL*NHEADS*4;
  float* A_cum  = (float*)w;  w += (size_t)B_SZ*NHEADS*NCHUNK*CHUNK*4;
  float* sc     = (float*)w;  w += (size_t)BL*4;

  // 0) all converts in one launch (Wg = W_out * norm_w, RMS fold)
  cvt_all<<<(NCVT+255)/256, 256, 0, stream>>>(u, W_in, W_out, norm_w, u_h, Win_h, Wg_h);
  // 1) zxbcdt = u @ W_in.T  (fp16 out; includes dt logit columns)
  gemm_f16_pipe<1><<<dim3(NPAD1/128, BL/128), 256, 0, stream>>>(u_h, Win_h, zx_h, nullptr, DPROJ, D_MODEL);
  // 2) dt + per-chunk cumsum (fused, shfl prefix)
  dtacum_kernel<<<B_SZ*NHEADS*NCHUNK, 64, 0, stream>>>(zx_h, dt_bias, A_log, dt, A_cum);
  // 3) depthwise conv + silu (fp16 in/out)
  conv8_kernel<<<((BL/8)*(CONV_DIM/4)+255)/256, 256, 0, stream>>>(zx_h, conv_w, conv_b, xBC_h);
  // 4) G = C B^T per (b,c), fp16 out
  g_kernel<<<B_SZ*NCHUNK*4, 256, 0, stream>>>(xBC_h, G);
  // 5) per-chunk states (MFMA, fp16 out)
  states_mfma<<<B_SZ*NCHUNK*NHEADS, 256, 0, stream>>>(xBC_h, dt, A_cum, states);
  // 6) inter-chunk scan (prefetch-all + serial recurrence), 8-way split
  scan_kernel<<<B_SZ*NHEADS*8, 256, 0, stream>>>(A_cum, states);
  // 7) Y (MFMA), fp16 out (unnormalized)
  y_mfma<<<B_SZ*NCHUNK*NHEADS, 256, 0, stream>>>(xBC_h, zx_h, dt, A_cum, G, states, Dp, ypre_h);
  // 8) per-row RMS scale
  rowsc_kernel<<<BL, 256, 0, stream>>>(ypre_h, sc);
  // 9) out = diag(sc) * (ypre @ (W_out*norm_w).T)  (64x128 tile, 3 blocks/CU)
  gemm_f16_64<<<dim3(D_MODEL/128, BL/64), 256, 0, stream>>>(ypre_h, Wg_h, out, sc, D_MODEL, D_INNER);
}